// Round 1
// baseline (1278.896 us; speedup 1.0000x reference)
//
#include <hip/hip_runtime.h>
#include <math.h>

#define NPTS 100000
#define NSAMP 16
#define NROWS (NPTS*NSAMP)
#define EPS 1e-5f

#define GRID_B 256
#define GRID_C 768
#define GRID_D 2048
#define GRID_E 1024

// stats layout (float offsets, relative to stats base `st`)
#define S_BN1A 0
#define S_BN1B 4
#define S_BN2A 8
#define S_BN2B 72
#define S_BN3A 136
#define S_BN3B 144
#define S_PARTB 160
#define S_PARTC (S_PARTB + GRID_B*8)
#define S_PARTD (S_PARTC + GRID_C*128)

// ---------------------------------------------------------------------------
// Kernel A: xq/xk/xv = x @ W + b  (three 100000x64 @ 64x64 GEMMs)
// block 256 = 16x16 threads, each owns a 4x4 micro-tile of a 64x64 block tile.
// ---------------------------------------------------------------------------
__global__ __launch_bounds__(256) void qkv_kernel(
    const float* __restrict__ x,
    const float* __restrict__ Wq, const float* __restrict__ bq,
    const float* __restrict__ Wk, const float* __restrict__ bk,
    const float* __restrict__ Wv, const float* __restrict__ bv,
    float* __restrict__ xq, float* __restrict__ xk, float* __restrict__ xv)
{
    __shared__ float wsh[64][64];
    const int tid = threadIdx.x;
    const int tr = tid >> 4, tc = tid & 15;
    const int r0 = blockIdx.x * 64;

    const float* Wm[3] = {Wq, Wk, Wv};
    const float* bm[3] = {bq, bk, bv};
    float* om[3] = {xq, xk, xv};

    int rows[4]; bool rok[4];
    #pragma unroll
    for (int rr = 0; rr < 4; ++rr) { rows[rr] = r0 + tr*4 + rr; rok[rr] = rows[rr] < NPTS; }

    for (int m = 0; m < 3; ++m) {
        __syncthreads();
        for (int l = tid; l < 4096; l += 256) wsh[l >> 6][l & 63] = Wm[m][l];
        __syncthreads();

        float acc[4][4];
        #pragma unroll
        for (int cc = 0; cc < 4; ++cc) {
            float bias = bm[m][tc*4 + cc];
            #pragma unroll
            for (int rr = 0; rr < 4; ++rr) acc[rr][cc] = bias;
        }

        for (int k4 = 0; k4 < 16; ++k4) {
            float xr[4][4];
            #pragma unroll
            for (int rr = 0; rr < 4; ++rr) {
                float4 t = rok[rr] ? *(const float4*)&x[(size_t)rows[rr]*64 + k4*4]
                                   : make_float4(0.f, 0.f, 0.f, 0.f);
                xr[rr][0] = t.x; xr[rr][1] = t.y; xr[rr][2] = t.z; xr[rr][3] = t.w;
            }
            float wr[4][4];
            #pragma unroll
            for (int kk = 0; kk < 4; ++kk) {
                float4 t = *(const float4*)&wsh[k4*4 + kk][tc*4];
                wr[kk][0] = t.x; wr[kk][1] = t.y; wr[kk][2] = t.z; wr[kk][3] = t.w;
            }
            #pragma unroll
            for (int kk = 0; kk < 4; ++kk)
                #pragma unroll
                for (int rr = 0; rr < 4; ++rr)
                    #pragma unroll
                    for (int cc = 0; cc < 4; ++cc)
                        acc[rr][cc] += xr[rr][kk] * wr[kk][cc];
        }

        #pragma unroll
        for (int rr = 0; rr < 4; ++rr) {
            if (rok[rr]) {
                float4 o;
                o.x = acc[rr][0]; o.y = acc[rr][1]; o.z = acc[rr][2]; o.w = acc[rr][3];
                *(float4*)&om[m][(size_t)rows[rr]*64 + tc*4] = o;
            }
        }
    }
}

// ---------------------------------------------------------------------------
// Kernel B: BN1 stats over t1 = (p[idx]-p) @ Wp1 + bp1   (3 channels)
// thread-per-row grid-stride; wave shuffle + block reduce -> per-block partial
// ---------------------------------------------------------------------------
__global__ __launch_bounds__(256) void bn1_stats_kernel(
    const float* __restrict__ p, const int* __restrict__ idx,
    const float* __restrict__ Wp1, const float* __restrict__ bp1,
    float* __restrict__ part)
{
    const int tid = threadIdx.x;
    float w9[9], bb[3];
    #pragma unroll
    for (int i = 0; i < 9; ++i) w9[i] = Wp1[i];
    #pragma unroll
    for (int i = 0; i < 3; ++i) bb[i] = bp1[i];

    float s0=0.f,s1=0.f,s2=0.f,q0=0.f,q1=0.f,q2=0.f;
    for (int row = blockIdx.x*blockDim.x + tid; row < NROWS; row += gridDim.x*blockDim.x) {
        const int n = row >> 4;
        const int j = idx[row];
        const float d0 = p[j*3+0] - p[n*3+0];
        const float d1 = p[j*3+1] - p[n*3+1];
        const float d2 = p[j*3+2] - p[n*3+2];
        const float t0 = d0*w9[0] + d1*w9[3] + d2*w9[6] + bb[0];
        const float t1 = d0*w9[1] + d1*w9[4] + d2*w9[7] + bb[1];
        const float t2 = d0*w9[2] + d1*w9[5] + d2*w9[8] + bb[2];
        s0 += t0; s1 += t1; s2 += t2;
        q0 += t0*t0; q1 += t1*t1; q2 += t2*t2;
    }
    #pragma unroll
    for (int m = 32; m >= 1; m >>= 1) {
        s0 += __shfl_xor(s0, m); s1 += __shfl_xor(s1, m); s2 += __shfl_xor(s2, m);
        q0 += __shfl_xor(q0, m); q1 += __shfl_xor(q1, m); q2 += __shfl_xor(q2, m);
    }
    __shared__ float red[4][6];
    const int lane = tid & 63, wid = tid >> 6;
    if (lane == 0) {
        red[wid][0]=s0; red[wid][1]=s1; red[wid][2]=s2;
        red[wid][3]=q0; red[wid][4]=q1; red[wid][5]=q2;
    }
    __syncthreads();
    if (tid < 6)
        part[blockIdx.x*8 + tid] = red[0][tid]+red[1][tid]+red[2][tid]+red[3][tid];
}

// ---------------------------------------------------------------------------
// Generic BN finalize: sum per-block partials, emit a = g*rsqrt(var+eps),
// b = beta - a*mean  (q partial stored at offset nch within each block slot)
// ---------------------------------------------------------------------------
__global__ void bn_fin_kernel(const float* __restrict__ part, int nblk, int stride, int nch,
                              const float* __restrict__ g, const float* __restrict__ beta,
                              float* __restrict__ aout, float* __restrict__ bout)
{
    const int c = threadIdx.x;
    if (c >= nch) return;
    float s = 0.f, q = 0.f;
    for (int b = 0; b < nblk; ++b) {
        s += part[(size_t)b*stride + c];
        q += part[(size_t)b*stride + nch + c];
    }
    const float inv = 1.0f / (float)NROWS;
    const float mean = s * inv;
    const float var = fmaxf(q * inv - mean*mean, 0.f);
    const float a = g[c] * rsqrtf(var + EPS);
    aout[c] = a;
    bout[c] = beta[c] - a * mean;
}

// ---------------------------------------------------------------------------
// Kernel C: BN2 stats over r_qk = xk[idx] - xq + p_r   (64 channels)
// wave-per-point, lane = channel; p_r recomputed from p gathers.
// ---------------------------------------------------------------------------
__global__ __launch_bounds__(256) void bn2_stats_kernel(
    const float* __restrict__ p, const int* __restrict__ idx,
    const float* __restrict__ xq, const float* __restrict__ xk,
    const float* __restrict__ Wp1, const float* __restrict__ bp1,
    const float* __restrict__ Wp2, const float* __restrict__ bp2,
    const float* __restrict__ st, float* __restrict__ part)
{
    const int tid = threadIdx.x, lane = tid & 63, wid = tid >> 6;
    float w9[9], bb[3], a1[3], b1[3];
    #pragma unroll
    for (int i = 0; i < 9; ++i) w9[i] = Wp1[i];
    #pragma unroll
    for (int i = 0; i < 3; ++i) { bb[i] = bp1[i]; a1[i] = st[S_BN1A+i]; b1[i] = st[S_BN1B+i]; }
    const float wc0 = Wp2[lane], wc1 = Wp2[64+lane], wc2 = Wp2[128+lane], bpc = bp2[lane];

    float s = 0.f, q = 0.f;
    const int nw = gridDim.x * 4;
    for (int pt = blockIdx.x*4 + wid; pt < NPTS; pt += nw) {
        const float xqc = xq[(size_t)pt*64 + lane];
        const float pn0 = p[pt*3], pn1 = p[pt*3+1], pn2 = p[pt*3+2];
        #pragma unroll 4
        for (int t = 0; t < 16; ++t) {
            const int j = idx[pt*16 + t];
            const float d0 = p[j*3] - pn0, d1 = p[j*3+1] - pn1, d2 = p[j*3+2] - pn2;
            const float t0 = d0*w9[0] + d1*w9[3] + d2*w9[6] + bb[0];
            const float t1 = d0*w9[1] + d1*w9[4] + d2*w9[7] + bb[1];
            const float t2 = d0*w9[2] + d1*w9[5] + d2*w9[8] + bb[2];
            const float h0 = fmaxf(a1[0]*t0 + b1[0], 0.f);
            const float h1 = fmaxf(a1[1]*t1 + b1[1], 0.f);
            const float h2 = fmaxf(a1[2]*t2 + b1[2], 0.f);
            const float pr = h0*wc0 + h1*wc1 + h2*wc2 + bpc;
            const float r = xk[(size_t)j*64 + lane] - xqc + pr;
            s += r; q += r*r;
        }
    }
    __shared__ float redS[4][64], redQ[4][64];
    redS[wid][lane] = s; redQ[wid][lane] = q;
    __syncthreads();
    if (tid < 64) {
        const float S = redS[0][tid]+redS[1][tid]+redS[2][tid]+redS[3][tid];
        const float Q = redQ[0][tid]+redQ[1][tid]+redQ[2][tid]+redQ[3][tid];
        part[(size_t)blockIdx.x*128 + tid] = S;
        part[(size_t)blockIdx.x*128 + 64 + tid] = Q;
    }
}

// ---------------------------------------------------------------------------
// Kernel D: w1 = relu(bn2(r_qk)) @ Ww1 + bww1  [NROWS, 8]  + BN3 stats
// 32-row tiles; h staged in LDS (padded 68 for conflict-free float4 reads)
// ---------------------------------------------------------------------------
__global__ __launch_bounds__(256) void w1_kernel(
    const float* __restrict__ p, const int* __restrict__ idx,
    const float* __restrict__ xq, const float* __restrict__ xk,
    const float* __restrict__ Wp1, const float* __restrict__ bp1,
    const float* __restrict__ Wp2, const float* __restrict__ bp2,
    const float* __restrict__ Ww1, const float* __restrict__ bww1,
    const float* __restrict__ st, float* __restrict__ w1out, float* __restrict__ part)
{
    __shared__ float hs[32][4];
    __shared__ __align__(16) float hbuf[32][68];
    __shared__ __align__(16) float wT[8][68];
    const int tid = threadIdx.x;

    for (int l = tid; l < 512; l += 256) wT[l & 7][l >> 3] = Ww1[l];

    float w9[9], bb[3], a1[3], b1[3];
    #pragma unroll
    for (int i = 0; i < 9; ++i) w9[i] = Wp1[i];
    #pragma unroll
    for (int i = 0; i < 3; ++i) { bb[i] = bp1[i]; a1[i] = st[S_BN1A+i]; b1[i] = st[S_BN1B+i]; }

    const int c = tid & 63;
    const float wc0 = Wp2[c], wc1 = Wp2[64+c], wc2 = Wp2[128+c], bpc = bp2[c];
    const float a2c = st[S_BN2A + c], b2c = st[S_BN2B + c];
    const int jch = tid & 7, rrow = tid >> 3;
    const float bw1j = bww1[jch];

    float s3 = 0.f, q3 = 0.f;
    const int ntiles = NROWS / 32;
    for (int tile = blockIdx.x; tile < ntiles; tile += gridDim.x) {
        const int row0 = tile * 32;
        __syncthreads();   // protect hs/hbuf reuse across iterations
        if (tid < 32) {
            const int row = row0 + tid;
            const int n = row >> 4;
            const int j = idx[row];
            const float d0 = p[j*3]-p[n*3], d1 = p[j*3+1]-p[n*3+1], d2 = p[j*3+2]-p[n*3+2];
            const float t0 = d0*w9[0] + d1*w9[3] + d2*w9[6] + bb[0];
            const float t1 = d0*w9[1] + d1*w9[4] + d2*w9[7] + bb[1];
            const float t2 = d0*w9[2] + d1*w9[5] + d2*w9[8] + bb[2];
            hs[tid][0] = fmaxf(a1[0]*t0 + b1[0], 0.f);
            hs[tid][1] = fmaxf(a1[1]*t1 + b1[1], 0.f);
            hs[tid][2] = fmaxf(a1[2]*t2 + b1[2], 0.f);
        }
        __syncthreads();
        #pragma unroll
        for (int pass = 0; pass < 8; ++pass) {
            const int rr = pass*4 + (tid >> 6);   // one row per wave per pass
            const int row = row0 + rr;
            const int n = row >> 4;
            const int j = idx[row];
            const float pr = hs[rr][0]*wc0 + hs[rr][1]*wc1 + hs[rr][2]*wc2 + bpc;
            const float r = xk[(size_t)j*64 + c] - xq[(size_t)n*64 + c] + pr;
            hbuf[rr][c] = fmaxf(a2c*r + b2c, 0.f);
        }
        __syncthreads();
        float acc = bw1j;
        const float4* hb4 = (const float4*)&hbuf[rrow][0];
        const float4* wt4 = (const float4*)&wT[jch][0];
        #pragma unroll
        for (int k = 0; k < 16; ++k) {
            const float4 h4 = hb4[k], v4 = wt4[k];
            acc += h4.x*v4.x + h4.y*v4.y + h4.z*v4.z + h4.w*v4.w;
        }
        w1out[(size_t)(row0 + rrow)*8 + jch] = acc;
        s3 += acc; q3 += acc*acc;
    }
    __shared__ float redS[32][8], redQ[32][8];
    redS[rrow][jch] = s3; redQ[rrow][jch] = q3;
    __syncthreads();
    if (tid < 8) {
        float S = 0.f, Q = 0.f;
        for (int i = 0; i < 32; ++i) { S += redS[i][tid]; Q += redQ[i][tid]; }
        part[(size_t)blockIdx.x*16 + tid] = S;
        part[(size_t)blockIdx.x*16 + 8 + tid] = Q;
    }
}

// ---------------------------------------------------------------------------
// Kernel E: w2 = relu(bn3(w1)) @ Ww2 + bww2; softmax over 16 neighbors;
// out[n,c] = sum_t (xv[idx]+p_r)[c] * w[t][c&7].  wave-per-point.
// ---------------------------------------------------------------------------
__global__ __launch_bounds__(256) void out_kernel(
    const float* __restrict__ p, const int* __restrict__ idx,
    const float* __restrict__ xv, const float* __restrict__ w1,
    const float* __restrict__ Wp1, const float* __restrict__ bp1,
    const float* __restrict__ Wp2, const float* __restrict__ bp2,
    const float* __restrict__ Ww2, const float* __restrict__ bww2,
    const float* __restrict__ st, float* __restrict__ out)
{
    const int tid = threadIdx.x, lane = tid & 63, wid = tid >> 6;
    const int j8 = lane & 7, t0 = lane >> 3;

    float w9[9], bb[3], a1[3], b1[3];
    #pragma unroll
    for (int i = 0; i < 9; ++i) w9[i] = Wp1[i];
    #pragma unroll
    for (int i = 0; i < 3; ++i) { bb[i] = bp1[i]; a1[i] = st[S_BN1A+i]; b1[i] = st[S_BN1B+i]; }
    float a3[8], b3[8], ww2c[8];
    #pragma unroll
    for (int i = 0; i < 8; ++i) {
        a3[i] = st[S_BN3A+i]; b3[i] = st[S_BN3B+i];
        ww2c[i] = Ww2[i*8 + j8];
    }
    const float bw2j = bww2[j8];
    const int c = lane;
    const float wc0 = Wp2[c], wc1 = Wp2[64+c], wc2 = Wp2[128+c], bpc = bp2[c];

    const int nw = gridDim.x * 4;
    for (int pt = blockIdx.x*4 + wid; pt < NPTS; pt += nw) {
        // phase 1: w2 for (t0, j8) and (t0+8, j8), then softmax over t per j8
        const float* w1r0 = &w1[(size_t)(pt*16 + t0)*8];
        float v0 = bw2j, v1 = bw2j;
        #pragma unroll
        for (int jj = 0; jj < 8; ++jj) {
            v0 += fmaxf(a3[jj]*w1r0[jj]      + b3[jj], 0.f) * ww2c[jj];
            v1 += fmaxf(a3[jj]*w1r0[64 + jj] + b3[jj], 0.f) * ww2c[jj];
        }
        float m = fmaxf(v0, v1);
        m = fmaxf(m, __shfl_xor(m, 8));
        m = fmaxf(m, __shfl_xor(m, 16));
        m = fmaxf(m, __shfl_xor(m, 32));
        float e0 = __expf(v0 - m), e1 = __expf(v1 - m);
        float ssum = e0 + e1;
        ssum += __shfl_xor(ssum, 8);
        ssum += __shfl_xor(ssum, 16);
        ssum += __shfl_xor(ssum, 32);
        const float inv = 1.0f / ssum;
        e0 *= inv; e1 *= inv;

        // phase 2: weighted sum over neighbors, lane = output channel
        const float pn0 = p[pt*3], pn1 = p[pt*3+1], pn2 = p[pt*3+2];
        float acc = 0.f;
        #pragma unroll
        for (int t = 0; t < 16; ++t) {
            const float wt = __shfl((t < 8) ? e0 : e1, ((t & 7) << 3) + j8);
            const int j = idx[pt*16 + t];
            const float d0 = p[j*3] - pn0, d1 = p[j*3+1] - pn1, d2 = p[j*3+2] - pn2;
            const float t1v = d0*w9[0] + d1*w9[3] + d2*w9[6] + bb[0];
            const float t2v = d0*w9[1] + d1*w9[4] + d2*w9[7] + bb[1];
            const float t3v = d0*w9[2] + d1*w9[5] + d2*w9[8] + bb[2];
            const float h0 = fmaxf(a1[0]*t1v + b1[0], 0.f);
            const float h1 = fmaxf(a1[1]*t2v + b1[1], 0.f);
            const float h2 = fmaxf(a1[2]*t3v + b1[2], 0.f);
            const float pr = h0*wc0 + h1*wc1 + h2*wc2 + bpc;
            acc += (xv[(size_t)j*64 + c] + pr) * wt;
        }
        out[(size_t)pt*64 + c] = acc;
    }
}

// ---------------------------------------------------------------------------
extern "C" void kernel_launch(void* const* d_in, const int* in_sizes, int n_in,
                              void* d_out, int out_size, void* d_ws, size_t ws_size,
                              hipStream_t stream)
{
    const float* p    = (const float*)d_in[0];
    const float* x    = (const float*)d_in[1];
    /* d_in[2] = o, unused (single batch) */
    const int*   idx  = (const int*)d_in[3];
    const float* Wq   = (const float*)d_in[4];
    const float* bq   = (const float*)d_in[5];
    const float* Wk   = (const float*)d_in[6];
    const float* bk   = (const float*)d_in[7];
    const float* Wv   = (const float*)d_in[8];
    const float* bv   = (const float*)d_in[9];
    const float* Wp1  = (const float*)d_in[10];
    const float* bp1  = (const float*)d_in[11];
    const float* gp   = (const float*)d_in[12];
    const float* betap= (const float*)d_in[13];
    const float* Wp2  = (const float*)d_in[14];
    const float* bp2  = (const float*)d_in[15];
    const float* gw1  = (const float*)d_in[16];
    const float* bw1  = (const float*)d_in[17];
    const float* Ww1  = (const float*)d_in[18];
    const float* bww1 = (const float*)d_in[19];
    const float* gw2  = (const float*)d_in[20];
    const float* bw2  = (const float*)d_in[21];
    const float* Ww2  = (const float*)d_in[22];
    const float* bww2 = (const float*)d_in[23];

    float* out = (float*)d_out;
    float* ws  = (float*)d_ws;

    // workspace layout (floats): xq | xk | xv | w1 | stats+partials  (~128.6 MB)
    float* xq = ws;
    float* xk = ws + (size_t)NPTS*64;
    float* xv = ws + (size_t)2*NPTS*64;
    float* w1 = ws + (size_t)3*NPTS*64;
    float* st = ws + (size_t)3*NPTS*64 + (size_t)NROWS*8;

    qkv_kernel<<<(NPTS + 63)/64, 256, 0, stream>>>(x, Wq, bq, Wk, bk, Wv, bv, xq, xk, xv);

    bn1_stats_kernel<<<GRID_B, 256, 0, stream>>>(p, idx, Wp1, bp1, st + S_PARTB);
    bn_fin_kernel<<<1, 64, 0, stream>>>(st + S_PARTB, GRID_B, 8, 3, gp, betap,
                                        st + S_BN1A, st + S_BN1B);

    bn2_stats_kernel<<<GRID_C, 256, 0, stream>>>(p, idx, xq, xk, Wp1, bp1, Wp2, bp2,
                                                 st, st + S_PARTC);
    bn_fin_kernel<<<1, 64, 0, stream>>>(st + S_PARTC, GRID_C, 128, 64, gw1, bw1,
                                        st + S_BN2A, st + S_BN2B);

    w1_kernel<<<GRID_D, 256, 0, stream>>>(p, idx, xq, xk, Wp1, bp1, Wp2, bp2,
                                          Ww1, bww1, st, w1, st + S_PARTD);
    bn_fin_kernel<<<1, 64, 0, stream>>>(st + S_PARTD, GRID_D, 16, 8, gw2, bw2,
                                        st + S_BN3A, st + S_BN3B);

    out_kernel<<<GRID_E, 256, 0, stream>>>(p, idx, xv, w1, Wp1, bp1, Wp2, bp2,
                                           Ww2, bww2, st, out);
}

// Round 2
// 758.530 us; speedup vs baseline: 1.6860x; 1.6860x over previous
//
#include <hip/hip_runtime.h>
#include <math.h>

#define NPTS 100000
#define NSAMP 16
#define NROWS (NPTS*NSAMP)
#define EPS 1e-5f

#define GRID_B 256
#define GRID_C 768
#define GRID_D 2048
#define GRID_E 1024

// stats layout (float offsets, relative to stats base `st`)
#define S_BN1A 0
#define S_BN1B 4
#define S_BN2A 8
#define S_BN2B 72
#define S_BN3A 136
#define S_BN3B 144
#define S_PARTB 160
#define S_PARTC (S_PARTB + GRID_B*8)
#define S_PARTD (S_PARTC + GRID_C*128)

// ---------------------------------------------------------------------------
// Kernel A: xq/xk/xv = x @ W + b  (three 100000x64 @ 64x64 GEMMs)
// ---------------------------------------------------------------------------
__global__ __launch_bounds__(256) void qkv_kernel(
    const float* __restrict__ x,
    const float* __restrict__ Wq, const float* __restrict__ bq,
    const float* __restrict__ Wk, const float* __restrict__ bk,
    const float* __restrict__ Wv, const float* __restrict__ bv,
    float* __restrict__ xq, float* __restrict__ xk, float* __restrict__ xv)
{
    __shared__ float wsh[64][64];
    const int tid = threadIdx.x;
    const int tr = tid >> 4, tc = tid & 15;
    const int r0 = blockIdx.x * 64;

    const float* Wm[3] = {Wq, Wk, Wv};
    const float* bm[3] = {bq, bk, bv};
    float* om[3] = {xq, xk, xv};

    int rows[4]; bool rok[4];
    #pragma unroll
    for (int rr = 0; rr < 4; ++rr) { rows[rr] = r0 + tr*4 + rr; rok[rr] = rows[rr] < NPTS; }

    for (int m = 0; m < 3; ++m) {
        __syncthreads();
        for (int l = tid; l < 4096; l += 256) wsh[l >> 6][l & 63] = Wm[m][l];
        __syncthreads();

        float acc[4][4];
        #pragma unroll
        for (int cc = 0; cc < 4; ++cc) {
            float bias = bm[m][tc*4 + cc];
            #pragma unroll
            for (int rr = 0; rr < 4; ++rr) acc[rr][cc] = bias;
        }

        for (int k4 = 0; k4 < 16; ++k4) {
            float xr[4][4];
            #pragma unroll
            for (int rr = 0; rr < 4; ++rr) {
                float4 t = rok[rr] ? *(const float4*)&x[(size_t)rows[rr]*64 + k4*4]
                                   : make_float4(0.f, 0.f, 0.f, 0.f);
                xr[rr][0] = t.x; xr[rr][1] = t.y; xr[rr][2] = t.z; xr[rr][3] = t.w;
            }
            float wr[4][4];
            #pragma unroll
            for (int kk = 0; kk < 4; ++kk) {
                float4 t = *(const float4*)&wsh[k4*4 + kk][tc*4];
                wr[kk][0] = t.x; wr[kk][1] = t.y; wr[kk][2] = t.z; wr[kk][3] = t.w;
            }
            #pragma unroll
            for (int kk = 0; kk < 4; ++kk)
                #pragma unroll
                for (int rr = 0; rr < 4; ++rr)
                    #pragma unroll
                    for (int cc = 0; cc < 4; ++cc)
                        acc[rr][cc] += xr[rr][kk] * wr[kk][cc];
        }

        #pragma unroll
        for (int rr = 0; rr < 4; ++rr) {
            if (rok[rr]) {
                float4 o;
                o.x = acc[rr][0]; o.y = acc[rr][1]; o.z = acc[rr][2]; o.w = acc[rr][3];
                *(float4*)&om[m][(size_t)rows[rr]*64 + tc*4] = o;
            }
        }
    }
}

// ---------------------------------------------------------------------------
// Kernel B: BN1 stats over t1 = (p[idx]-p) @ Wp1 + bp1   (3 channels)
// ---------------------------------------------------------------------------
__global__ __launch_bounds__(256) void bn1_stats_kernel(
    const float* __restrict__ p, const int* __restrict__ idx,
    const float* __restrict__ Wp1, const float* __restrict__ bp1,
    float* __restrict__ part)
{
    const int tid = threadIdx.x;
    float w9[9], bb[3];
    #pragma unroll
    for (int i = 0; i < 9; ++i) w9[i] = Wp1[i];
    #pragma unroll
    for (int i = 0; i < 3; ++i) bb[i] = bp1[i];

    float s0=0.f,s1=0.f,s2=0.f,q0=0.f,q1=0.f,q2=0.f;
    for (int row = blockIdx.x*blockDim.x + tid; row < NROWS; row += gridDim.x*blockDim.x) {
        const int n = row >> 4;
        const int j = idx[row];
        const float d0 = p[j*3+0] - p[n*3+0];
        const float d1 = p[j*3+1] - p[n*3+1];
        const float d2 = p[j*3+2] - p[n*3+2];
        const float t0 = d0*w9[0] + d1*w9[3] + d2*w9[6] + bb[0];
        const float t1 = d0*w9[1] + d1*w9[4] + d2*w9[7] + bb[1];
        const float t2 = d0*w9[2] + d1*w9[5] + d2*w9[8] + bb[2];
        s0 += t0; s1 += t1; s2 += t2;
        q0 += t0*t0; q1 += t1*t1; q2 += t2*t2;
    }
    #pragma unroll
    for (int m = 32; m >= 1; m >>= 1) {
        s0 += __shfl_xor(s0, m); s1 += __shfl_xor(s1, m); s2 += __shfl_xor(s2, m);
        q0 += __shfl_xor(q0, m); q1 += __shfl_xor(q1, m); q2 += __shfl_xor(q2, m);
    }
    __shared__ float red[4][6];
    const int lane = tid & 63, wid = tid >> 6;
    if (lane == 0) {
        red[wid][0]=s0; red[wid][1]=s1; red[wid][2]=s2;
        red[wid][3]=q0; red[wid][4]=q1; red[wid][5]=q2;
    }
    __syncthreads();
    if (tid < 6)
        part[blockIdx.x*8 + tid] = red[0][tid]+red[1][tid]+red[2][tid]+red[3][tid];
}

// ---------------------------------------------------------------------------
// BN finalize: one block per channel, 256 threads grid-stride over partials.
// a = g*rsqrt(var+eps), b = beta - a*mean
// ---------------------------------------------------------------------------
__global__ __launch_bounds__(256) void bn_fin_kernel(
    const float* __restrict__ part, int nblk, int stride, int nch,
    const float* __restrict__ g, const float* __restrict__ beta,
    float* __restrict__ aout, float* __restrict__ bout)
{
    const int c = blockIdx.x;           // channel
    const int tid = threadIdx.x;
    float s = 0.f, q = 0.f;
    for (int b = tid; b < nblk; b += 256) {
        s += part[(size_t)b*stride + c];
        q += part[(size_t)b*stride + nch + c];
    }
    #pragma unroll
    for (int m = 32; m >= 1; m >>= 1) { s += __shfl_xor(s, m); q += __shfl_xor(q, m); }
    __shared__ float rs[4], rq[4];
    if ((tid & 63) == 0) { rs[tid >> 6] = s; rq[tid >> 6] = q; }
    __syncthreads();
    if (tid == 0) {
        s = rs[0]+rs[1]+rs[2]+rs[3];
        q = rq[0]+rq[1]+rq[2]+rq[3];
        const float inv = 1.0f / (float)NROWS;
        const float mean = s * inv;
        const float var = fmaxf(q * inv - mean*mean, 0.f);
        const float a = g[c] * rsqrtf(var + EPS);
        aout[c] = a;
        bout[c] = beta[c] - a * mean;
    }
}

// ---------------------------------------------------------------------------
// Kernel C: BN2 stats over r_qk = xk[idx] - xq + p_r   (64 channels)
// ---------------------------------------------------------------------------
__global__ __launch_bounds__(256) void bn2_stats_kernel(
    const float* __restrict__ p, const int* __restrict__ idx,
    const float* __restrict__ xq, const float* __restrict__ xk,
    const float* __restrict__ Wp1, const float* __restrict__ bp1,
    const float* __restrict__ Wp2, const float* __restrict__ bp2,
    const float* __restrict__ st, float* __restrict__ part)
{
    const int tid = threadIdx.x, lane = tid & 63, wid = tid >> 6;
    float w9[9], bb[3], a1[3], b1[3];
    #pragma unroll
    for (int i = 0; i < 9; ++i) w9[i] = Wp1[i];
    #pragma unroll
    for (int i = 0; i < 3; ++i) { bb[i] = bp1[i]; a1[i] = st[S_BN1A+i]; b1[i] = st[S_BN1B+i]; }
    const float wc0 = Wp2[lane], wc1 = Wp2[64+lane], wc2 = Wp2[128+lane], bpc = bp2[lane];

    float s = 0.f, q = 0.f;
    const int nw = gridDim.x * 4;
    for (int pt = blockIdx.x*4 + wid; pt < NPTS; pt += nw) {
        const float xqc = xq[(size_t)pt*64 + lane];
        const float pn0 = p[pt*3], pn1 = p[pt*3+1], pn2 = p[pt*3+2];
        #pragma unroll 4
        for (int t = 0; t < 16; ++t) {
            const int j = idx[pt*16 + t];
            const float d0 = p[j*3] - pn0, d1 = p[j*3+1] - pn1, d2 = p[j*3+2] - pn2;
            const float t0 = d0*w9[0] + d1*w9[3] + d2*w9[6] + bb[0];
            const float t1 = d0*w9[1] + d1*w9[4] + d2*w9[7] + bb[1];
            const float t2 = d0*w9[2] + d1*w9[5] + d2*w9[8] + bb[2];
            const float h0 = fmaxf(a1[0]*t0 + b1[0], 0.f);
            const float h1 = fmaxf(a1[1]*t1 + b1[1], 0.f);
            const float h2 = fmaxf(a1[2]*t2 + b1[2], 0.f);
            const float pr = h0*wc0 + h1*wc1 + h2*wc2 + bpc;
            const float r = xk[(size_t)j*64 + lane] - xqc + pr;
            s += r; q += r*r;
        }
    }
    __shared__ float redS[4][64], redQ[4][64];
    redS[wid][lane] = s; redQ[wid][lane] = q;
    __syncthreads();
    if (tid < 64) {
        const float S = redS[0][tid]+redS[1][tid]+redS[2][tid]+redS[3][tid];
        const float Q = redQ[0][tid]+redQ[1][tid]+redQ[2][tid]+redQ[3][tid];
        part[(size_t)blockIdx.x*128 + tid] = S;
        part[(size_t)blockIdx.x*128 + 64 + tid] = Q;
    }
}

// ---------------------------------------------------------------------------
// Kernel D: w1 = relu(bn2(r_qk)) @ Ww1 + bww1  [NROWS, 8]  + BN3 stats
// ---------------------------------------------------------------------------
__global__ __launch_bounds__(256) void w1_kernel(
    const float* __restrict__ p, const int* __restrict__ idx,
    const float* __restrict__ xq, const float* __restrict__ xk,
    const float* __restrict__ Wp1, const float* __restrict__ bp1,
    const float* __restrict__ Wp2, const float* __restrict__ bp2,
    const float* __restrict__ Ww1, const float* __restrict__ bww1,
    const float* __restrict__ st, float* __restrict__ w1out, float* __restrict__ part)
{
    __shared__ float hs[32][4];
    __shared__ __align__(16) float hbuf[32][68];
    __shared__ __align__(16) float wT[8][68];
    const int tid = threadIdx.x;

    for (int l = tid; l < 512; l += 256) wT[l & 7][l >> 3] = Ww1[l];

    float w9[9], bb[3], a1[3], b1[3];
    #pragma unroll
    for (int i = 0; i < 9; ++i) w9[i] = Wp1[i];
    #pragma unroll
    for (int i = 0; i < 3; ++i) { bb[i] = bp1[i]; a1[i] = st[S_BN1A+i]; b1[i] = st[S_BN1B+i]; }

    const int c = tid & 63;
    const float wc0 = Wp2[c], wc1 = Wp2[64+c], wc2 = Wp2[128+c], bpc = bp2[c];
    const float a2c = st[S_BN2A + c], b2c = st[S_BN2B + c];
    const int jch = tid & 7, rrow = tid >> 3;
    const float bw1j = bww1[jch];

    float s3 = 0.f, q3 = 0.f;
    const int ntiles = NROWS / 32;
    for (int tile = blockIdx.x; tile < ntiles; tile += gridDim.x) {
        const int row0 = tile * 32;
        __syncthreads();   // protect hs/hbuf reuse across iterations
        if (tid < 32) {
            const int row = row0 + tid;
            const int n = row >> 4;
            const int j = idx[row];
            const float d0 = p[j*3]-p[n*3], d1 = p[j*3+1]-p[n*3+1], d2 = p[j*3+2]-p[n*3+2];
            const float t0 = d0*w9[0] + d1*w9[3] + d2*w9[6] + bb[0];
            const float t1 = d0*w9[1] + d1*w9[4] + d2*w9[7] + bb[1];
            const float t2 = d0*w9[2] + d1*w9[5] + d2*w9[8] + bb[2];
            hs[tid][0] = fmaxf(a1[0]*t0 + b1[0], 0.f);
            hs[tid][1] = fmaxf(a1[1]*t1 + b1[1], 0.f);
            hs[tid][2] = fmaxf(a1[2]*t2 + b1[2], 0.f);
        }
        __syncthreads();
        #pragma unroll
        for (int pass = 0; pass < 8; ++pass) {
            const int rr = pass*4 + (tid >> 6);   // one row per wave per pass
            const int row = row0 + rr;
            const int n = row >> 4;
            const int j = idx[row];
            const float pr = hs[rr][0]*wc0 + hs[rr][1]*wc1 + hs[rr][2]*wc2 + bpc;
            const float r = xk[(size_t)j*64 + c] - xq[(size_t)n*64 + c] + pr;
            hbuf[rr][c] = fmaxf(a2c*r + b2c, 0.f);
        }
        __syncthreads();
        float acc = bw1j;
        const float4* hb4 = (const float4*)&hbuf[rrow][0];
        const float4* wt4 = (const float4*)&wT[jch][0];
        #pragma unroll
        for (int k = 0; k < 16; ++k) {
            const float4 h4 = hb4[k], v4 = wt4[k];
            acc += h4.x*v4.x + h4.y*v4.y + h4.z*v4.z + h4.w*v4.w;
        }
        w1out[(size_t)(row0 + rrow)*8 + jch] = acc;
        s3 += acc; q3 += acc*acc;
    }
    __shared__ float redS[32][8], redQ[32][8];
    redS[rrow][jch] = s3; redQ[rrow][jch] = q3;
    __syncthreads();
    if (tid < 8) {
        float S = 0.f, Q = 0.f;
        for (int i = 0; i < 32; ++i) { S += redS[i][tid]; Q += redQ[i][tid]; }
        part[(size_t)blockIdx.x*16 + tid] = S;
        part[(size_t)blockIdx.x*16 + 8 + tid] = Q;
    }
}

// ---------------------------------------------------------------------------
// Kernel E: w2 = relu(bn3(w1)) @ Ww2 + bww2; softmax; weighted sum.
// ---------------------------------------------------------------------------
__global__ __launch_bounds__(256) void out_kernel(
    const float* __restrict__ p, const int* __restrict__ idx,
    const float* __restrict__ xv, const float* __restrict__ w1,
    const float* __restrict__ Wp1, const float* __restrict__ bp1,
    const float* __restrict__ Wp2, const float* __restrict__ bp2,
    const float* __restrict__ Ww2, const float* __restrict__ bww2,
    const float* __restrict__ st, float* __restrict__ out)
{
    const int tid = threadIdx.x, lane = tid & 63, wid = tid >> 6;
    const int j8 = lane & 7, t0 = lane >> 3;

    float w9[9], bb[3], a1[3], b1[3];
    #pragma unroll
    for (int i = 0; i < 9; ++i) w9[i] = Wp1[i];
    #pragma unroll
    for (int i = 0; i < 3; ++i) { bb[i] = bp1[i]; a1[i] = st[S_BN1A+i]; b1[i] = st[S_BN1B+i]; }
    float a3[8], b3[8], ww2c[8];
    #pragma unroll
    for (int i = 0; i < 8; ++i) {
        a3[i] = st[S_BN3A+i]; b3[i] = st[S_BN3B+i];
        ww2c[i] = Ww2[i*8 + j8];
    }
    const float bw2j = bww2[j8];
    const int c = lane;
    const float wc0 = Wp2[c], wc1 = Wp2[64+c], wc2 = Wp2[128+c], bpc = bp2[c];

    const int nw = gridDim.x * 4;
    for (int pt = blockIdx.x*4 + wid; pt < NPTS; pt += nw) {
        const float* w1r0 = &w1[(size_t)(pt*16 + t0)*8];
        float v0 = bw2j, v1 = bw2j;
        #pragma unroll
        for (int jj = 0; jj < 8; ++jj) {
            v0 += fmaxf(a3[jj]*w1r0[jj]      + b3[jj], 0.f) * ww2c[jj];
            v1 += fmaxf(a3[jj]*w1r0[64 + jj] + b3[jj], 0.f) * ww2c[jj];
        }
        float m = fmaxf(v0, v1);
        m = fmaxf(m, __shfl_xor(m, 8));
        m = fmaxf(m, __shfl_xor(m, 16));
        m = fmaxf(m, __shfl_xor(m, 32));
        float e0 = __expf(v0 - m), e1 = __expf(v1 - m);
        float ssum = e0 + e1;
        ssum += __shfl_xor(ssum, 8);
        ssum += __shfl_xor(ssum, 16);
        ssum += __shfl_xor(ssum, 32);
        const float inv = 1.0f / ssum;
        e0 *= inv; e1 *= inv;

        const float pn0 = p[pt*3], pn1 = p[pt*3+1], pn2 = p[pt*3+2];
        float acc = 0.f;
        #pragma unroll
        for (int t = 0; t < 16; ++t) {
            const float wt = __shfl((t < 8) ? e0 : e1, ((t & 7) << 3) + j8);
            const int j = idx[pt*16 + t];
            const float d0 = p[j*3] - pn0, d1 = p[j*3+1] - pn1, d2 = p[j*3+2] - pn2;
            const float t1v = d0*w9[0] + d1*w9[3] + d2*w9[6] + bb[0];
            const float t2v = d0*w9[1] + d1*w9[4] + d2*w9[7] + bb[1];
            const float t3v = d0*w9[2] + d1*w9[5] + d2*w9[8] + bb[2];
            const float h0 = fmaxf(a1[0]*t1v + b1[0], 0.f);
            const float h1 = fmaxf(a1[1]*t2v + b1[1], 0.f);
            const float h2 = fmaxf(a1[2]*t3v + b1[2], 0.f);
            const float pr = h0*wc0 + h1*wc1 + h2*wc2 + bpc;
            acc += (xv[(size_t)j*64 + c] + pr) * wt;
        }
        out[(size_t)pt*64 + c] = acc;
    }
}

// ---------------------------------------------------------------------------
extern "C" void kernel_launch(void* const* d_in, const int* in_sizes, int n_in,
                              void* d_out, int out_size, void* d_ws, size_t ws_size,
                              hipStream_t stream)
{
    const float* p    = (const float*)d_in[0];
    const float* x    = (const float*)d_in[1];
    const int*   idx  = (const int*)d_in[3];
    const float* Wq   = (const float*)d_in[4];
    const float* bq   = (const float*)d_in[5];
    const float* Wk   = (const float*)d_in[6];
    const float* bk   = (const float*)d_in[7];
    const float* Wv   = (const float*)d_in[8];
    const float* bv   = (const float*)d_in[9];
    const float* Wp1  = (const float*)d_in[10];
    const float* bp1  = (const float*)d_in[11];
    const float* gp   = (const float*)d_in[12];
    const float* betap= (const float*)d_in[13];
    const float* Wp2  = (const float*)d_in[14];
    const float* bp2  = (const float*)d_in[15];
    const float* gw1  = (const float*)d_in[16];
    const float* bw1  = (const float*)d_in[17];
    const float* Ww1  = (const float*)d_in[18];
    const float* bww1 = (const float*)d_in[19];
    const float* gw2  = (const float*)d_in[20];
    const float* bw2  = (const float*)d_in[21];
    const float* Ww2  = (const float*)d_in[22];
    const float* bww2 = (const float*)d_in[23];

    float* out = (float*)d_out;
    float* ws  = (float*)d_ws;

    float* xq = ws;
    float* xk = ws + (size_t)NPTS*64;
    float* xv = ws + (size_t)2*NPTS*64;
    float* w1 = ws + (size_t)3*NPTS*64;
    float* st = ws + (size_t)3*NPTS*64 + (size_t)NROWS*8;

    qkv_kernel<<<(NPTS + 63)/64, 256, 0, stream>>>(x, Wq, bq, Wk, bk, Wv, bv, xq, xk, xv);

    bn1_stats_kernel<<<GRID_B, 256, 0, stream>>>(p, idx, Wp1, bp1, st + S_PARTB);
    bn_fin_kernel<<<3, 256, 0, stream>>>(st + S_PARTB, GRID_B, 8, 3, gp, betap,
                                         st + S_BN1A, st + S_BN1B);

    bn2_stats_kernel<<<GRID_C, 256, 0, stream>>>(p, idx, xq, xk, Wp1, bp1, Wp2, bp2,
                                                 st, st + S_PARTC);
    bn_fin_kernel<<<64, 256, 0, stream>>>(st + S_PARTC, GRID_C, 128, 64, gw1, bw1,
                                          st + S_BN2A, st + S_BN2B);

    w1_kernel<<<GRID_D, 256, 0, stream>>>(p, idx, xq, xk, Wp1, bp1, Wp2, bp2,
                                          Ww1, bww1, st, w1, st + S_PARTD);
    bn_fin_kernel<<<8, 256, 0, stream>>>(st + S_PARTD, GRID_D, 16, 8, gw2, bw2,
                                         st + S_BN3A, st + S_BN3B);

    out_kernel<<<GRID_E, 256, 0, stream>>>(p, idx, xv, w1, Wp1, bp1, Wp2, bp2,
                                           Ww2, bww2, st, out);
}

// Round 3
// 604.905 us; speedup vs baseline: 2.1142x; 1.2540x over previous
//
#include <hip/hip_runtime.h>
#include <math.h>

#define NPTS 100000
#define NSAMP 16
#define NROWS (NPTS*NSAMP)
#define EPS 1e-5f

#define GRID_B 256
#define GRID_C 768
#define GRID_D 2048
#define GRID_E 1024

// stats layout (float offsets, relative to stats base `st`)
#define S_BN1A 0
#define S_BN1B 4
#define S_BN2A 8
#define S_BN2B 72
#define S_BN3A 136
#define S_BN3B 144
#define S_PARTB 160
#define S_PARTC (S_PARTB + GRID_B*8)
#define S_PARTD (S_PARTC + GRID_C*128)

// ---------------------------------------------------------------------------
// Kernel A: xq/xk/xv = x @ W + b.  grid = (row_tiles, 3); blockIdx.y picks
// which of q/k/v this block computes (uniform -> SGPR select, no ptr array).
// 16x16 threads, 4x4 micro-tile each, 64-row tile. unroll capped to keep
// VGPRs low (round-2 version hit 256 VGPR / 10% occupancy -> 285 us).
// ---------------------------------------------------------------------------
__global__ __launch_bounds__(256) void qkv_kernel(
    const float* __restrict__ x,
    const float* __restrict__ Wq, const float* __restrict__ bq,
    const float* __restrict__ Wk, const float* __restrict__ bk,
    const float* __restrict__ Wv, const float* __restrict__ bv,
    float* __restrict__ xq, float* __restrict__ xk, float* __restrict__ xv)
{
    const int m = blockIdx.y;
    const float* __restrict__ W  = (m == 0) ? Wq : (m == 1) ? Wk : Wv;
    const float* __restrict__ bs = (m == 0) ? bq : (m == 1) ? bk : bv;
    float* __restrict__ om       = (m == 0) ? xq : (m == 1) ? xk : xv;

    __shared__ float wsh[64][64];
    const int tid = threadIdx.x;
    for (int l = tid; l < 4096; l += 256) wsh[l >> 6][l & 63] = W[l];
    __syncthreads();

    const int tr = tid >> 4, tc = tid & 15;
    const int r0 = blockIdx.x * 64;

    int rows[4]; bool rok[4];
    #pragma unroll
    for (int rr = 0; rr < 4; ++rr) { rows[rr] = r0 + tr*4 + rr; rok[rr] = rows[rr] < NPTS; }

    float acc[4][4];
    #pragma unroll
    for (int cc = 0; cc < 4; ++cc) {
        const float bias = bs[tc*4 + cc];
        #pragma unroll
        for (int rr = 0; rr < 4; ++rr) acc[rr][cc] = bias;
    }

    #pragma unroll 4
    for (int k4 = 0; k4 < 16; ++k4) {
        float xr[4][4];
        #pragma unroll
        for (int rr = 0; rr < 4; ++rr) {
            float4 t = rok[rr] ? *(const float4*)&x[(size_t)rows[rr]*64 + k4*4]
                               : make_float4(0.f, 0.f, 0.f, 0.f);
            xr[rr][0] = t.x; xr[rr][1] = t.y; xr[rr][2] = t.z; xr[rr][3] = t.w;
        }
        float wr[4][4];
        #pragma unroll
        for (int kk = 0; kk < 4; ++kk) {
            float4 t = *(const float4*)&wsh[k4*4 + kk][tc*4];
            wr[kk][0] = t.x; wr[kk][1] = t.y; wr[kk][2] = t.z; wr[kk][3] = t.w;
        }
        #pragma unroll
        for (int kk = 0; kk < 4; ++kk)
            #pragma unroll
            for (int rr = 0; rr < 4; ++rr)
                #pragma unroll
                for (int cc = 0; cc < 4; ++cc)
                    acc[rr][cc] += xr[rr][kk] * wr[kk][cc];
    }

    #pragma unroll
    for (int rr = 0; rr < 4; ++rr) {
        if (rok[rr]) {
            float4 o;
            o.x = acc[rr][0]; o.y = acc[rr][1]; o.z = acc[rr][2]; o.w = acc[rr][3];
            *(float4*)&om[(size_t)rows[rr]*64 + tc*4] = o;
        }
    }
}

// ---------------------------------------------------------------------------
// Kernel B: BN1 stats over t1 = (p[idx]-p) @ Wp1 + bp1   (3 channels)
// ---------------------------------------------------------------------------
__global__ __launch_bounds__(256) void bn1_stats_kernel(
    const float* __restrict__ p, const int* __restrict__ idx,
    const float* __restrict__ Wp1, const float* __restrict__ bp1,
    float* __restrict__ part)
{
    const int tid = threadIdx.x;
    float w9[9], bb[3];
    #pragma unroll
    for (int i = 0; i < 9; ++i) w9[i] = Wp1[i];
    #pragma unroll
    for (int i = 0; i < 3; ++i) bb[i] = bp1[i];

    float s0=0.f,s1=0.f,s2=0.f,q0=0.f,q1=0.f,q2=0.f;
    for (int row = blockIdx.x*blockDim.x + tid; row < NROWS; row += gridDim.x*blockDim.x) {
        const int n = row >> 4;
        const int j = idx[row];
        const float d0 = p[j*3+0] - p[n*3+0];
        const float d1 = p[j*3+1] - p[n*3+1];
        const float d2 = p[j*3+2] - p[n*3+2];
        const float t0 = d0*w9[0] + d1*w9[3] + d2*w9[6] + bb[0];
        const float t1 = d0*w9[1] + d1*w9[4] + d2*w9[7] + bb[1];
        const float t2 = d0*w9[2] + d1*w9[5] + d2*w9[8] + bb[2];
        s0 += t0; s1 += t1; s2 += t2;
        q0 += t0*t0; q1 += t1*t1; q2 += t2*t2;
    }
    #pragma unroll
    for (int m = 32; m >= 1; m >>= 1) {
        s0 += __shfl_xor(s0, m); s1 += __shfl_xor(s1, m); s2 += __shfl_xor(s2, m);
        q0 += __shfl_xor(q0, m); q1 += __shfl_xor(q1, m); q2 += __shfl_xor(q2, m);
    }
    __shared__ float red[4][6];
    const int lane = tid & 63, wid = tid >> 6;
    if (lane == 0) {
        red[wid][0]=s0; red[wid][1]=s1; red[wid][2]=s2;
        red[wid][3]=q0; red[wid][4]=q1; red[wid][5]=q2;
    }
    __syncthreads();
    if (tid < 6)
        part[blockIdx.x*8 + tid] = red[0][tid]+red[1][tid]+red[2][tid]+red[3][tid];
}

// ---------------------------------------------------------------------------
// BN finalize: one block per channel, 256 threads grid-stride over partials.
// ---------------------------------------------------------------------------
__global__ __launch_bounds__(256) void bn_fin_kernel(
    const float* __restrict__ part, int nblk, int stride, int nch,
    const float* __restrict__ g, const float* __restrict__ beta,
    float* __restrict__ aout, float* __restrict__ bout)
{
    const int c = blockIdx.x;
    const int tid = threadIdx.x;
    float s = 0.f, q = 0.f;
    for (int b = tid; b < nblk; b += 256) {
        s += part[(size_t)b*stride + c];
        q += part[(size_t)b*stride + nch + c];
    }
    #pragma unroll
    for (int m = 32; m >= 1; m >>= 1) { s += __shfl_xor(s, m); q += __shfl_xor(q, m); }
    __shared__ float rs[4], rq[4];
    if ((tid & 63) == 0) { rs[tid >> 6] = s; rq[tid >> 6] = q; }
    __syncthreads();
    if (tid == 0) {
        s = rs[0]+rs[1]+rs[2]+rs[3];
        q = rq[0]+rq[1]+rq[2]+rq[3];
        const float inv = 1.0f / (float)NROWS;
        const float mean = s * inv;
        const float var = fmaxf(q * inv - mean*mean, 0.f);
        const float a = g[c] * rsqrtf(var + EPS);
        aout[c] = a;
        bout[c] = beta[c] - a * mean;
    }
}

// ---------------------------------------------------------------------------
// Kernel C: BN2 stats over r_qk = xk[idx] - xq + p_r   (64 channels)
// ---------------------------------------------------------------------------
__global__ __launch_bounds__(256) void bn2_stats_kernel(
    const float* __restrict__ p, const int* __restrict__ idx,
    const float* __restrict__ xq, const float* __restrict__ xk,
    const float* __restrict__ Wp1, const float* __restrict__ bp1,
    const float* __restrict__ Wp2, const float* __restrict__ bp2,
    const float* __restrict__ st, float* __restrict__ part)
{
    const int tid = threadIdx.x, lane = tid & 63, wid = tid >> 6;
    float w9[9], bb[3], a1[3], b1[3];
    #pragma unroll
    for (int i = 0; i < 9; ++i) w9[i] = Wp1[i];
    #pragma unroll
    for (int i = 0; i < 3; ++i) { bb[i] = bp1[i]; a1[i] = st[S_BN1A+i]; b1[i] = st[S_BN1B+i]; }
    const float wc0 = Wp2[lane], wc1 = Wp2[64+lane], wc2 = Wp2[128+lane], bpc = bp2[lane];

    float s = 0.f, q = 0.f;
    const int nw = gridDim.x * 4;
    for (int pt = blockIdx.x*4 + wid; pt < NPTS; pt += nw) {
        const float xqc = xq[(size_t)pt*64 + lane];
        const float pn0 = p[pt*3], pn1 = p[pt*3+1], pn2 = p[pt*3+2];
        #pragma unroll 4
        for (int t = 0; t < 16; ++t) {
            const int j = idx[pt*16 + t];
            const float d0 = p[j*3] - pn0, d1 = p[j*3+1] - pn1, d2 = p[j*3+2] - pn2;
            const float t0 = d0*w9[0] + d1*w9[3] + d2*w9[6] + bb[0];
            const float t1 = d0*w9[1] + d1*w9[4] + d2*w9[7] + bb[1];
            const float t2 = d0*w9[2] + d1*w9[5] + d2*w9[8] + bb[2];
            const float h0 = fmaxf(a1[0]*t0 + b1[0], 0.f);
            const float h1 = fmaxf(a1[1]*t1 + b1[1], 0.f);
            const float h2 = fmaxf(a1[2]*t2 + b1[2], 0.f);
            const float pr = h0*wc0 + h1*wc1 + h2*wc2 + bpc;
            const float r = xk[(size_t)j*64 + lane] - xqc + pr;
            s += r; q += r*r;
        }
    }
    __shared__ float redS[4][64], redQ[4][64];
    redS[wid][lane] = s; redQ[wid][lane] = q;
    __syncthreads();
    if (tid < 64) {
        const float S = redS[0][tid]+redS[1][tid]+redS[2][tid]+redS[3][tid];
        const float Q = redQ[0][tid]+redQ[1][tid]+redQ[2][tid]+redQ[3][tid];
        part[(size_t)blockIdx.x*128 + tid] = S;
        part[(size_t)blockIdx.x*128 + 64 + tid] = Q;
    }
}

// ---------------------------------------------------------------------------
// Kernel D: w1 = relu(bn2(r_qk)) @ Ww1 + bww1  [NROWS, 8]  + BN3 stats
// ---------------------------------------------------------------------------
__global__ __launch_bounds__(256) void w1_kernel(
    const float* __restrict__ p, const int* __restrict__ idx,
    const float* __restrict__ xq, const float* __restrict__ xk,
    const float* __restrict__ Wp1, const float* __restrict__ bp1,
    const float* __restrict__ Wp2, const float* __restrict__ bp2,
    const float* __restrict__ Ww1, const float* __restrict__ bww1,
    const float* __restrict__ st, float* __restrict__ w1out, float* __restrict__ part)
{
    __shared__ float hs[32][4];
    __shared__ __align__(16) float hbuf[32][68];
    __shared__ __align__(16) float wT[8][68];
    const int tid = threadIdx.x;

    for (int l = tid; l < 512; l += 256) wT[l & 7][l >> 3] = Ww1[l];

    float w9[9], bb[3], a1[3], b1[3];
    #pragma unroll
    for (int i = 0; i < 9; ++i) w9[i] = Wp1[i];
    #pragma unroll
    for (int i = 0; i < 3; ++i) { bb[i] = bp1[i]; a1[i] = st[S_BN1A+i]; b1[i] = st[S_BN1B+i]; }

    const int c = tid & 63;
    const float wc0 = Wp2[c], wc1 = Wp2[64+c], wc2 = Wp2[128+c], bpc = bp2[c];
    const float a2c = st[S_BN2A + c], b2c = st[S_BN2B + c];
    const int jch = tid & 7, rrow = tid >> 3;
    const float bw1j = bww1[jch];

    float s3 = 0.f, q3 = 0.f;
    const int ntiles = NROWS / 32;
    for (int tile = blockIdx.x; tile < ntiles; tile += gridDim.x) {
        const int row0 = tile * 32;
        __syncthreads();
        if (tid < 32) {
            const int row = row0 + tid;
            const int n = row >> 4;
            const int j = idx[row];
            const float d0 = p[j*3]-p[n*3], d1 = p[j*3+1]-p[n*3+1], d2 = p[j*3+2]-p[n*3+2];
            const float t0 = d0*w9[0] + d1*w9[3] + d2*w9[6] + bb[0];
            const float t1 = d0*w9[1] + d1*w9[4] + d2*w9[7] + bb[1];
            const float t2 = d0*w9[2] + d1*w9[5] + d2*w9[8] + bb[2];
            hs[tid][0] = fmaxf(a1[0]*t0 + b1[0], 0.f);
            hs[tid][1] = fmaxf(a1[1]*t1 + b1[1], 0.f);
            hs[tid][2] = fmaxf(a1[2]*t2 + b1[2], 0.f);
        }
        __syncthreads();
        #pragma unroll
        for (int pass = 0; pass < 8; ++pass) {
            const int rr = pass*4 + (tid >> 6);
            const int row = row0 + rr;
            const int n = row >> 4;
            const int j = idx[row];
            const float pr = hs[rr][0]*wc0 + hs[rr][1]*wc1 + hs[rr][2]*wc2 + bpc;
            const float r = xk[(size_t)j*64 + c] - xq[(size_t)n*64 + c] + pr;
            hbuf[rr][c] = fmaxf(a2c*r + b2c, 0.f);
        }
        __syncthreads();
        float acc = bw1j;
        const float4* hb4 = (const float4*)&hbuf[rrow][0];
        const float4* wt4 = (const float4*)&wT[jch][0];
        #pragma unroll
        for (int k = 0; k < 16; ++k) {
            const float4 h4 = hb4[k], v4 = wt4[k];
            acc += h4.x*v4.x + h4.y*v4.y + h4.z*v4.z + h4.w*v4.w;
        }
        w1out[(size_t)(row0 + rrow)*8 + jch] = acc;
        s3 += acc; q3 += acc*acc;
    }
    __shared__ float redS[32][8], redQ[32][8];
    redS[rrow][jch] = s3; redQ[rrow][jch] = q3;
    __syncthreads();
    if (tid < 8) {
        float S = 0.f, Q = 0.f;
        for (int i = 0; i < 32; ++i) { S += redS[i][tid]; Q += redQ[i][tid]; }
        part[(size_t)blockIdx.x*16 + tid] = S;
        part[(size_t)blockIdx.x*16 + 8 + tid] = Q;
    }
}

// ---------------------------------------------------------------------------
// Kernel E: w2 = relu(bn3(w1)) @ Ww2 + bww2; softmax; weighted sum.
// ---------------------------------------------------------------------------
__global__ __launch_bounds__(256) void out_kernel(
    const float* __restrict__ p, const int* __restrict__ idx,
    const float* __restrict__ xv, const float* __restrict__ w1,
    const float* __restrict__ Wp1, const float* __restrict__ bp1,
    const float* __restrict__ Wp2, const float* __restrict__ bp2,
    const float* __restrict__ Ww2, const float* __restrict__ bww2,
    const float* __restrict__ st, float* __restrict__ out)
{
    const int tid = threadIdx.x, lane = tid & 63, wid = tid >> 6;
    const int j8 = lane & 7, t0 = lane >> 3;

    float w9[9], bb[3], a1[3], b1[3];
    #pragma unroll
    for (int i = 0; i < 9; ++i) w9[i] = Wp1[i];
    #pragma unroll
    for (int i = 0; i < 3; ++i) { bb[i] = bp1[i]; a1[i] = st[S_BN1A+i]; b1[i] = st[S_BN1B+i]; }
    float a3[8], b3[8], ww2c[8];
    #pragma unroll
    for (int i = 0; i < 8; ++i) {
        a3[i] = st[S_BN3A+i]; b3[i] = st[S_BN3B+i];
        ww2c[i] = Ww2[i*8 + j8];
    }
    const float bw2j = bww2[j8];
    const int c = lane;
    const float wc0 = Wp2[c], wc1 = Wp2[64+c], wc2 = Wp2[128+c], bpc = bp2[c];

    const int nw = gridDim.x * 4;
    for (int pt = blockIdx.x*4 + wid; pt < NPTS; pt += nw) {
        const float* w1r0 = &w1[(size_t)(pt*16 + t0)*8];
        float v0 = bw2j, v1 = bw2j;
        #pragma unroll
        for (int jj = 0; jj < 8; ++jj) {
            v0 += fmaxf(a3[jj]*w1r0[jj]      + b3[jj], 0.f) * ww2c[jj];
            v1 += fmaxf(a3[jj]*w1r0[64 + jj] + b3[jj], 0.f) * ww2c[jj];
        }
        float m = fmaxf(v0, v1);
        m = fmaxf(m, __shfl_xor(m, 8));
        m = fmaxf(m, __shfl_xor(m, 16));
        m = fmaxf(m, __shfl_xor(m, 32));
        float e0 = __expf(v0 - m), e1 = __expf(v1 - m);
        float ssum = e0 + e1;
        ssum += __shfl_xor(ssum, 8);
        ssum += __shfl_xor(ssum, 16);
        ssum += __shfl_xor(ssum, 32);
        const float inv = 1.0f / ssum;
        e0 *= inv; e1 *= inv;

        const float pn0 = p[pt*3], pn1 = p[pt*3+1], pn2 = p[pt*3+2];
        float acc = 0.f;
        #pragma unroll
        for (int t = 0; t < 16; ++t) {
            const float wt = __shfl((t < 8) ? e0 : e1, ((t & 7) << 3) + j8);
            const int j = idx[pt*16 + t];
            const float d0 = p[j*3] - pn0, d1 = p[j*3+1] - pn1, d2 = p[j*3+2] - pn2;
            const float t1v = d0*w9[0] + d1*w9[3] + d2*w9[6] + bb[0];
            const float t2v = d0*w9[1] + d1*w9[4] + d2*w9[7] + bb[1];
            const float t3v = d0*w9[2] + d1*w9[5] + d2*w9[8] + bb[2];
            const float h0 = fmaxf(a1[0]*t1v + b1[0], 0.f);
            const float h1 = fmaxf(a1[1]*t2v + b1[1], 0.f);
            const float h2 = fmaxf(a1[2]*t3v + b1[2], 0.f);
            const float pr = h0*wc0 + h1*wc1 + h2*wc2 + bpc;
            acc += (xv[(size_t)j*64 + c] + pr) * wt;
        }
        out[(size_t)pt*64 + c] = acc;
    }
}

// ---------------------------------------------------------------------------
extern "C" void kernel_launch(void* const* d_in, const int* in_sizes, int n_in,
                              void* d_out, int out_size, void* d_ws, size_t ws_size,
                              hipStream_t stream)
{
    const float* p    = (const float*)d_in[0];
    const float* x    = (const float*)d_in[1];
    const int*   idx  = (const int*)d_in[3];
    const float* Wq   = (const float*)d_in[4];
    const float* bq   = (const float*)d_in[5];
    const float* Wk   = (const float*)d_in[6];
    const float* bk   = (const float*)d_in[7];
    const float* Wv   = (const float*)d_in[8];
    const float* bv   = (const float*)d_in[9];
    const float* Wp1  = (const float*)d_in[10];
    const float* bp1  = (const float*)d_in[11];
    const float* gp   = (const float*)d_in[12];
    const float* betap= (const float*)d_in[13];
    const float* Wp2  = (const float*)d_in[14];
    const float* bp2  = (const float*)d_in[15];
    const float* gw1  = (const float*)d_in[16];
    const float* bw1  = (const float*)d_in[17];
    const float* Ww1  = (const float*)d_in[18];
    const float* bww1 = (const float*)d_in[19];
    const float* gw2  = (const float*)d_in[20];
    const float* bw2  = (const float*)d_in[21];
    const float* Ww2  = (const float*)d_in[22];
    const float* bww2 = (const float*)d_in[23];

    float* out = (float*)d_out;
    float* ws  = (float*)d_ws;

    float* xq = ws;
    float* xk = ws + (size_t)NPTS*64;
    float* xv = ws + (size_t)2*NPTS*64;
    float* w1 = ws + (size_t)3*NPTS*64;
    float* st = ws + (size_t)3*NPTS*64 + (size_t)NROWS*8;

    dim3 gq((NPTS + 63)/64, 3);
    qkv_kernel<<<gq, 256, 0, stream>>>(x, Wq, bq, Wk, bk, Wv, bv, xq, xk, xv);

    bn1_stats_kernel<<<GRID_B, 256, 0, stream>>>(p, idx, Wp1, bp1, st + S_PARTB);
    bn_fin_kernel<<<3, 256, 0, stream>>>(st + S_PARTB, GRID_B, 8, 3, gp, betap,
                                         st + S_BN1A, st + S_BN1B);

    bn2_stats_kernel<<<GRID_C, 256, 0, stream>>>(p, idx, xq, xk, Wp1, bp1, Wp2, bp2,
                                                 st, st + S_PARTC);
    bn_fin_kernel<<<64, 256, 0, stream>>>(st + S_PARTC, GRID_C, 128, 64, gw1, bw1,
                                          st + S_BN2A, st + S_BN2B);

    w1_kernel<<<GRID_D, 256, 0, stream>>>(p, idx, xq, xk, Wp1, bp1, Wp2, bp2,
                                          Ww1, bww1, st, w1, st + S_PARTD);
    bn_fin_kernel<<<8, 256, 0, stream>>>(st + S_PARTD, GRID_D, 16, 8, gw2, bw2,
                                         st + S_BN3A, st + S_BN3B);

    out_kernel<<<GRID_E, 256, 0, stream>>>(p, idx, xv, w1, Wp1, bp1, Wp2, bp2,
                                           Ww2, bww2, st, out);
}

// Round 4
// 416.805 us; speedup vs baseline: 3.0683x; 1.4513x over previous
//
#include <hip/hip_runtime.h>
#include <math.h>

#define NPTS 100000
#define NSAMP 16
#define NROWS (NPTS*NSAMP)
#define EPS 1e-5f

#define GRID_B 256
#define GRID_C 2048
#define GRID_D 2048
#define GRID_E 2048

// stats layout (float offsets, relative to stats base `st`)
#define S_BN1A 0
#define S_BN1B 4
#define S_BN2A 8
#define S_BN2B 72
#define S_BN3A 136
#define S_BN3B 144
#define S_PARTB 160
#define S_PARTC (S_PARTB + GRID_B*8)
#define S_PARTD (S_PARTC + GRID_C*128)

// ---------------------------------------------------------------------------
// Kernel A: xq/xk/xv = x @ W + b.  grid = (row_tiles, 3).
// ---------------------------------------------------------------------------
__global__ __launch_bounds__(256) void qkv_kernel(
    const float* __restrict__ x,
    const float* __restrict__ Wq, const float* __restrict__ bq,
    const float* __restrict__ Wk, const float* __restrict__ bk,
    const float* __restrict__ Wv, const float* __restrict__ bv,
    float* __restrict__ xq, float* __restrict__ xk, float* __restrict__ xv)
{
    const int m = blockIdx.y;
    const float* __restrict__ W  = (m == 0) ? Wq : (m == 1) ? Wk : Wv;
    const float* __restrict__ bs = (m == 0) ? bq : (m == 1) ? bk : bv;
    float* __restrict__ om       = (m == 0) ? xq : (m == 1) ? xk : xv;

    __shared__ float wsh[64][64];
    const int tid = threadIdx.x;
    for (int l = tid; l < 4096; l += 256) wsh[l >> 6][l & 63] = W[l];
    __syncthreads();

    const int tr = tid >> 4, tc = tid & 15;
    const int r0 = blockIdx.x * 64;

    int rows[4]; bool rok[4];
    #pragma unroll
    for (int rr = 0; rr < 4; ++rr) { rows[rr] = r0 + tr*4 + rr; rok[rr] = rows[rr] < NPTS; }

    float acc[4][4];
    #pragma unroll
    for (int cc = 0; cc < 4; ++cc) {
        const float bias = bs[tc*4 + cc];
        #pragma unroll
        for (int rr = 0; rr < 4; ++rr) acc[rr][cc] = bias;
    }

    #pragma unroll 4
    for (int k4 = 0; k4 < 16; ++k4) {
        float xr[4][4];
        #pragma unroll
        for (int rr = 0; rr < 4; ++rr) {
            float4 t = rok[rr] ? *(const float4*)&x[(size_t)rows[rr]*64 + k4*4]
                               : make_float4(0.f, 0.f, 0.f, 0.f);
            xr[rr][0] = t.x; xr[rr][1] = t.y; xr[rr][2] = t.z; xr[rr][3] = t.w;
        }
        float wr[4][4];
        #pragma unroll
        for (int kk = 0; kk < 4; ++kk) {
            float4 t = *(const float4*)&wsh[k4*4 + kk][tc*4];
            wr[kk][0] = t.x; wr[kk][1] = t.y; wr[kk][2] = t.z; wr[kk][3] = t.w;
        }
        #pragma unroll
        for (int kk = 0; kk < 4; ++kk)
            #pragma unroll
            for (int rr = 0; rr < 4; ++rr)
                #pragma unroll
                for (int cc = 0; cc < 4; ++cc)
                    acc[rr][cc] += xr[rr][kk] * wr[kk][cc];
    }

    #pragma unroll
    for (int rr = 0; rr < 4; ++rr) {
        if (rok[rr]) {
            float4 o;
            o.x = acc[rr][0]; o.y = acc[rr][1]; o.z = acc[rr][2]; o.w = acc[rr][3];
            *(float4*)&om[(size_t)rows[rr]*64 + tc*4] = o;
        }
    }
}

// ---------------------------------------------------------------------------
// Kernel B: BN1 stats over t1 = (p[idx]-p) @ Wp1 + bp1   (3 channels)
// ---------------------------------------------------------------------------
__global__ __launch_bounds__(256) void bn1_stats_kernel(
    const float* __restrict__ p, const int* __restrict__ idx,
    const float* __restrict__ Wp1, const float* __restrict__ bp1,
    float* __restrict__ part)
{
    const int tid = threadIdx.x;
    float w9[9], bb[3];
    #pragma unroll
    for (int i = 0; i < 9; ++i) w9[i] = Wp1[i];
    #pragma unroll
    for (int i = 0; i < 3; ++i) bb[i] = bp1[i];

    float s0=0.f,s1=0.f,s2=0.f,q0=0.f,q1=0.f,q2=0.f;
    for (int row = blockIdx.x*blockDim.x + tid; row < NROWS; row += gridDim.x*blockDim.x) {
        const int n = row >> 4;
        const int j = idx[row];
        const float d0 = p[j*3+0] - p[n*3+0];
        const float d1 = p[j*3+1] - p[n*3+1];
        const float d2 = p[j*3+2] - p[n*3+2];
        const float t0 = d0*w9[0] + d1*w9[3] + d2*w9[6] + bb[0];
        const float t1 = d0*w9[1] + d1*w9[4] + d2*w9[7] + bb[1];
        const float t2 = d0*w9[2] + d1*w9[5] + d2*w9[8] + bb[2];
        s0 += t0; s1 += t1; s2 += t2;
        q0 += t0*t0; q1 += t1*t1; q2 += t2*t2;
    }
    #pragma unroll
    for (int m = 32; m >= 1; m >>= 1) {
        s0 += __shfl_xor(s0, m); s1 += __shfl_xor(s1, m); s2 += __shfl_xor(s2, m);
        q0 += __shfl_xor(q0, m); q1 += __shfl_xor(q1, m); q2 += __shfl_xor(q2, m);
    }
    __shared__ float red[4][6];
    const int lane = tid & 63, wid = tid >> 6;
    if (lane == 0) {
        red[wid][0]=s0; red[wid][1]=s1; red[wid][2]=s2;
        red[wid][3]=q0; red[wid][4]=q1; red[wid][5]=q2;
    }
    __syncthreads();
    if (tid < 6)
        part[blockIdx.x*8 + tid] = red[0][tid]+red[1][tid]+red[2][tid]+red[3][tid];
}

// ---------------------------------------------------------------------------
// BN finalize: one block per channel, 256 threads grid-stride over partials.
// ---------------------------------------------------------------------------
__global__ __launch_bounds__(256) void bn_fin_kernel(
    const float* __restrict__ part, int nblk, int stride, int nch,
    const float* __restrict__ g, const float* __restrict__ beta,
    float* __restrict__ aout, float* __restrict__ bout)
{
    const int c = blockIdx.x;
    const int tid = threadIdx.x;
    float s = 0.f, q = 0.f;
    for (int b = tid; b < nblk; b += 256) {
        s += part[(size_t)b*stride + c];
        q += part[(size_t)b*stride + nch + c];
    }
    #pragma unroll
    for (int m = 32; m >= 1; m >>= 1) { s += __shfl_xor(s, m); q += __shfl_xor(q, m); }
    __shared__ float rs[4], rq[4];
    if ((tid & 63) == 0) { rs[tid >> 6] = s; rq[tid >> 6] = q; }
    __syncthreads();
    if (tid == 0) {
        s = rs[0]+rs[1]+rs[2]+rs[3];
        q = rq[0]+rq[1]+rq[2]+rq[3];
        const float inv = 1.0f / (float)NROWS;
        const float mean = s * inv;
        const float var = fmaxf(q * inv - mean*mean, 0.f);
        const float a = g[c] * rsqrtf(var + EPS);
        aout[c] = a;
        bout[c] = beta[c] - a * mean;
    }
}

// ---------------------------------------------------------------------------
// Kernel C: BN2 stats over r_qk = xk[idx] - xq + p_r   (64 channels)
// wave-per-point; lanes 0..15 compute the wave-uniform p_r trunk h(t) once,
// phase 2 rebuilds per-channel pr via shuffles (was 64x-redundant VALU).
// ---------------------------------------------------------------------------
__global__ __launch_bounds__(256) void bn2_stats_kernel(
    const float* __restrict__ p, const int* __restrict__ idx,
    const float* __restrict__ xq, const float* __restrict__ xk,
    const float* __restrict__ Wp1, const float* __restrict__ bp1,
    const float* __restrict__ Wp2, const float* __restrict__ bp2,
    const float* __restrict__ st, float* __restrict__ part)
{
    const int tid = threadIdx.x, lane = tid & 63, wid = tid >> 6;
    float w9[9], bb[3], a1[3], b1[3];
    #pragma unroll
    for (int i = 0; i < 9; ++i) w9[i] = Wp1[i];
    #pragma unroll
    for (int i = 0; i < 3; ++i) { bb[i] = bp1[i]; a1[i] = st[S_BN1A+i]; b1[i] = st[S_BN1B+i]; }
    const float wc0 = Wp2[lane], wc1 = Wp2[64+lane], wc2 = Wp2[128+lane], bpc = bp2[lane];

    float s = 0.f, q = 0.f;
    const int nw = gridDim.x * 4;
    for (int pt = blockIdx.x*4 + wid; pt < NPTS; pt += nw) {
        const float xqc = xq[(size_t)pt*64 + lane];
        int jreg = 0; float h0 = 0.f, h1 = 0.f, h2 = 0.f;
        if (lane < 16) {
            jreg = idx[pt*16 + lane];
            const float pn0 = p[pt*3], pn1 = p[pt*3+1], pn2 = p[pt*3+2];
            const float d0 = p[jreg*3] - pn0, d1 = p[jreg*3+1] - pn1, d2 = p[jreg*3+2] - pn2;
            const float t0 = d0*w9[0] + d1*w9[3] + d2*w9[6] + bb[0];
            const float t1 = d0*w9[1] + d1*w9[4] + d2*w9[7] + bb[1];
            const float t2 = d0*w9[2] + d1*w9[5] + d2*w9[8] + bb[2];
            h0 = fmaxf(a1[0]*t0 + b1[0], 0.f);
            h1 = fmaxf(a1[1]*t1 + b1[1], 0.f);
            h2 = fmaxf(a1[2]*t2 + b1[2], 0.f);
        }
        #pragma unroll
        for (int t = 0; t < 16; ++t) {
            const int j = __shfl(jreg, t);
            const float g0 = __shfl(h0, t), g1 = __shfl(h1, t), g2 = __shfl(h2, t);
            const float pr = g0*wc0 + g1*wc1 + g2*wc2 + bpc;
            const float r = xk[(size_t)j*64 + lane] - xqc + pr;
            s += r; q += r*r;
        }
    }
    __shared__ float redS[4][64], redQ[4][64];
    redS[wid][lane] = s; redQ[wid][lane] = q;
    __syncthreads();
    if (tid < 64) {
        const float S = redS[0][tid]+redS[1][tid]+redS[2][tid]+redS[3][tid];
        const float Q = redQ[0][tid]+redQ[1][tid]+redQ[2][tid]+redQ[3][tid];
        part[(size_t)blockIdx.x*128 + tid] = S;
        part[(size_t)blockIdx.x*128 + 64 + tid] = Q;
    }
}

// ---------------------------------------------------------------------------
// Kernel D: w1 = relu(bn2(r_qk)) @ Ww1 + bww1  [NROWS, 8]  + BN3 stats
// ---------------------------------------------------------------------------
__global__ __launch_bounds__(256) void w1_kernel(
    const float* __restrict__ p, const int* __restrict__ idx,
    const float* __restrict__ xq, const float* __restrict__ xk,
    const float* __restrict__ Wp1, const float* __restrict__ bp1,
    const float* __restrict__ Wp2, const float* __restrict__ bp2,
    const float* __restrict__ Ww1, const float* __restrict__ bww1,
    const float* __restrict__ st, float* __restrict__ w1out, float* __restrict__ part)
{
    __shared__ float hs[32][4];
    __shared__ __align__(16) float hbuf[32][68];
    __shared__ __align__(16) float wT[8][68];
    const int tid = threadIdx.x;

    for (int l = tid; l < 512; l += 256) wT[l & 7][l >> 3] = Ww1[l];

    float w9[9], bb[3], a1[3], b1[3];
    #pragma unroll
    for (int i = 0; i < 9; ++i) w9[i] = Wp1[i];
    #pragma unroll
    for (int i = 0; i < 3; ++i) { bb[i] = bp1[i]; a1[i] = st[S_BN1A+i]; b1[i] = st[S_BN1B+i]; }

    const int c = tid & 63;
    const float wc0 = Wp2[c], wc1 = Wp2[64+c], wc2 = Wp2[128+c], bpc = bp2[c];
    const float a2c = st[S_BN2A + c], b2c = st[S_BN2B + c];
    const int jch = tid & 7, rrow = tid >> 3;
    const float bw1j = bww1[jch];

    float s3 = 0.f, q3 = 0.f;
    const int ntiles = NROWS / 32;
    for (int tile = blockIdx.x; tile < ntiles; tile += gridDim.x) {
        const int row0 = tile * 32;
        __syncthreads();
        if (tid < 32) {
            const int row = row0 + tid;
            const int n = row >> 4;
            const int j = idx[row];
            const float d0 = p[j*3]-p[n*3], d1 = p[j*3+1]-p[n*3+1], d2 = p[j*3+2]-p[n*3+2];
            const float t0 = d0*w9[0] + d1*w9[3] + d2*w9[6] + bb[0];
            const float t1 = d0*w9[1] + d1*w9[4] + d2*w9[7] + bb[1];
            const float t2 = d0*w9[2] + d1*w9[5] + d2*w9[8] + bb[2];
            hs[tid][0] = fmaxf(a1[0]*t0 + b1[0], 0.f);
            hs[tid][1] = fmaxf(a1[1]*t1 + b1[1], 0.f);
            hs[tid][2] = fmaxf(a1[2]*t2 + b1[2], 0.f);
        }
        __syncthreads();
        #pragma unroll
        for (int pass = 0; pass < 8; ++pass) {
            const int rr = pass*4 + (tid >> 6);
            const int row = row0 + rr;
            const int n = row >> 4;
            const int j = idx[row];
            const float pr = hs[rr][0]*wc0 + hs[rr][1]*wc1 + hs[rr][2]*wc2 + bpc;
            const float r = xk[(size_t)j*64 + c] - xq[(size_t)n*64 + c] + pr;
            hbuf[rr][c] = fmaxf(a2c*r + b2c, 0.f);
        }
        __syncthreads();
        float acc = bw1j;
        const float4* hb4 = (const float4*)&hbuf[rrow][0];
        const float4* wt4 = (const float4*)&wT[jch][0];
        #pragma unroll
        for (int k = 0; k < 16; ++k) {
            const float4 h4 = hb4[k], v4 = wt4[k];
            acc += h4.x*v4.x + h4.y*v4.y + h4.z*v4.z + h4.w*v4.w;
        }
        w1out[(size_t)(row0 + rrow)*8 + jch] = acc;
        s3 += acc; q3 += acc*acc;
    }
    __shared__ float redS[32][8], redQ[32][8];
    redS[rrow][jch] = s3; redQ[rrow][jch] = q3;
    __syncthreads();
    if (tid < 8) {
        float S = 0.f, Q = 0.f;
        for (int i = 0; i < 32; ++i) { S += redS[i][tid]; Q += redQ[i][tid]; }
        part[(size_t)blockIdx.x*16 + tid] = S;
        part[(size_t)blockIdx.x*16 + 8 + tid] = Q;
    }
}

// ---------------------------------------------------------------------------
// Kernel E: w2 = relu(bn3(w1)) @ Ww2 + bww2; softmax; weighted sum.
// lanes 0..15 compute the p_r trunk once; phase 2 uses shuffles.
// ---------------------------------------------------------------------------
__global__ __launch_bounds__(256) void out_kernel(
    const float* __restrict__ p, const int* __restrict__ idx,
    const float* __restrict__ xv, const float* __restrict__ w1,
    const float* __restrict__ Wp1, const float* __restrict__ bp1,
    const float* __restrict__ Wp2, const float* __restrict__ bp2,
    const float* __restrict__ Ww2, const float* __restrict__ bww2,
    const float* __restrict__ st, float* __restrict__ out)
{
    const int tid = threadIdx.x, lane = tid & 63, wid = tid >> 6;
    const int j8 = lane & 7, t0 = lane >> 3;

    float w9[9], bb[3], a1[3], b1[3];
    #pragma unroll
    for (int i = 0; i < 9; ++i) w9[i] = Wp1[i];
    #pragma unroll
    for (int i = 0; i < 3; ++i) { bb[i] = bp1[i]; a1[i] = st[S_BN1A+i]; b1[i] = st[S_BN1B+i]; }
    float a3[8], b3[8], ww2c[8];
    #pragma unroll
    for (int i = 0; i < 8; ++i) {
        a3[i] = st[S_BN3A+i]; b3[i] = st[S_BN3B+i];
        ww2c[i] = Ww2[i*8 + j8];
    }
    const float bw2j = bww2[j8];
    const int c = lane;
    const float wc0 = Wp2[c], wc1 = Wp2[64+c], wc2 = Wp2[128+c], bpc = bp2[c];

    const int nw = gridDim.x * 4;
    for (int pt = blockIdx.x*4 + wid; pt < NPTS; pt += nw) {
        // phase 0: lanes 0..15 compute h(t), j(t) for neighbor t = lane
        int jreg = 0; float h0 = 0.f, h1 = 0.f, h2 = 0.f;
        if (lane < 16) {
            jreg = idx[pt*16 + lane];
            const float pn0 = p[pt*3], pn1 = p[pt*3+1], pn2 = p[pt*3+2];
            const float d0 = p[jreg*3] - pn0, d1 = p[jreg*3+1] - pn1, d2 = p[jreg*3+2] - pn2;
            const float t1v = d0*w9[0] + d1*w9[3] + d2*w9[6] + bb[0];
            const float t2v = d0*w9[1] + d1*w9[4] + d2*w9[7] + bb[1];
            const float t3v = d0*w9[2] + d1*w9[5] + d2*w9[8] + bb[2];
            h0 = fmaxf(a1[0]*t1v + b1[0], 0.f);
            h1 = fmaxf(a1[1]*t2v + b1[1], 0.f);
            h2 = fmaxf(a1[2]*t3v + b1[2], 0.f);
        }

        // phase 1: w2 for (t0, j8) and (t0+8, j8), softmax over t per j8
        const float* w1r0 = &w1[(size_t)(pt*16 + t0)*8];
        float v0 = bw2j, v1 = bw2j;
        #pragma unroll
        for (int jj = 0; jj < 8; ++jj) {
            v0 += fmaxf(a3[jj]*w1r0[jj]      + b3[jj], 0.f) * ww2c[jj];
            v1 += fmaxf(a3[jj]*w1r0[64 + jj] + b3[jj], 0.f) * ww2c[jj];
        }
        float m = fmaxf(v0, v1);
        m = fmaxf(m, __shfl_xor(m, 8));
        m = fmaxf(m, __shfl_xor(m, 16));
        m = fmaxf(m, __shfl_xor(m, 32));
        float e0 = __expf(v0 - m), e1 = __expf(v1 - m);
        float ssum = e0 + e1;
        ssum += __shfl_xor(ssum, 8);
        ssum += __shfl_xor(ssum, 16);
        ssum += __shfl_xor(ssum, 32);
        const float inv = 1.0f / ssum;
        e0 *= inv; e1 *= inv;

        // phase 2: weighted sum over neighbors, lane = output channel
        float acc = 0.f;
        #pragma unroll
        for (int t = 0; t < 16; ++t) {
            const int j = __shfl(jreg, t);
            const float g0 = __shfl(h0, t), g1 = __shfl(h1, t), g2 = __shfl(h2, t);
            const float pr = g0*wc0 + g1*wc1 + g2*wc2 + bpc;
            const float wt = __shfl((t < 8) ? e0 : e1, ((t & 7) << 3) + j8);
            acc += (xv[(size_t)j*64 + c] + pr) * wt;
        }
        out[(size_t)pt*64 + c] = acc;
    }
}

// ---------------------------------------------------------------------------
extern "C" void kernel_launch(void* const* d_in, const int* in_sizes, int n_in,
                              void* d_out, int out_size, void* d_ws, size_t ws_size,
                              hipStream_t stream)
{
    const float* p    = (const float*)d_in[0];
    const float* x    = (const float*)d_in[1];
    const int*   idx  = (const int*)d_in[3];
    const float* Wq   = (const float*)d_in[4];
    const float* bq   = (const float*)d_in[5];
    const float* Wk   = (const float*)d_in[6];
    const float* bk   = (const float*)d_in[7];
    const float* Wv   = (const float*)d_in[8];
    const float* bv   = (const float*)d_in[9];
    const float* Wp1  = (const float*)d_in[10];
    const float* bp1  = (const float*)d_in[11];
    const float* gp   = (const float*)d_in[12];
    const float* betap= (const float*)d_in[13];
    const float* Wp2  = (const float*)d_in[14];
    const float* bp2  = (const float*)d_in[15];
    const float* gw1  = (const float*)d_in[16];
    const float* bw1  = (const float*)d_in[17];
    const float* Ww1  = (const float*)d_in[18];
    const float* bww1 = (const float*)d_in[19];
    const float* gw2  = (const float*)d_in[20];
    const float* bw2  = (const float*)d_in[21];
    const float* Ww2  = (const float*)d_in[22];
    const float* bww2 = (const float*)d_in[23];

    float* out = (float*)d_out;
    float* ws  = (float*)d_ws;

    float* xq = ws;
    float* xk = ws + (size_t)NPTS*64;
    float* xv = ws + (size_t)2*NPTS*64;
    float* w1 = ws + (size_t)3*NPTS*64;
    float* st = ws + (size_t)3*NPTS*64 + (size_t)NROWS*8;

    dim3 gq((NPTS + 63)/64, 3);
    qkv_kernel<<<gq, 256, 0, stream>>>(x, Wq, bq, Wk, bk, Wv, bv, xq, xk, xv);

    bn1_stats_kernel<<<GRID_B, 256, 0, stream>>>(p, idx, Wp1, bp1, st + S_PARTB);
    bn_fin_kernel<<<3, 256, 0, stream>>>(st + S_PARTB, GRID_B, 8, 3, gp, betap,
                                         st + S_BN1A, st + S_BN1B);

    bn2_stats_kernel<<<GRID_C, 256, 0, stream>>>(p, idx, xq, xk, Wp1, bp1, Wp2, bp2,
                                                 st, st + S_PARTC);
    bn_fin_kernel<<<64, 256, 0, stream>>>(st + S_PARTC, GRID_C, 128, 64, gw1, bw1,
                                          st + S_BN2A, st + S_BN2B);

    w1_kernel<<<GRID_D, 256, 0, stream>>>(p, idx, xq, xk, Wp1, bp1, Wp2, bp2,
                                          Ww1, bww1, st, w1, st + S_PARTD);
    bn_fin_kernel<<<8, 256, 0, stream>>>(st + S_PARTD, GRID_D, 16, 8, gw2, bw2,
                                         st + S_BN3A, st + S_BN3B);

    out_kernel<<<GRID_E, 256, 0, stream>>>(p, idx, xv, w1, Wp1, bp1, Wp2, bp2,
                                           Ww2, bww2, st, out);
}

// Round 5
// 361.116 us; speedup vs baseline: 3.5415x; 1.1542x over previous
//
#include <hip/hip_runtime.h>
#include <math.h>

#define NPTS 100000
#define NSAMP 16
#define NROWS (NPTS*NSAMP)
#define EPS 1e-5f

#define GRID_B 256
#define GRID_C 2048
#define GRID_D 2048
#define GRID_E 2048

// stats layout (float offsets, relative to stats base `st`)
#define S_BN1A 0
#define S_BN1B 4
#define S_BN2A 8
#define S_BN2B 72
#define S_BN3A 136
#define S_BN3B 144
#define S_PARTB 160
#define S_PARTC (S_PARTB + GRID_B*8)
#define S_PARTD (S_PARTC + GRID_C*128)

// ---------------------------------------------------------------------------
// Kernel A: xq/xk/xv = x @ W + b.  One block = 64 rows; x staged in LDS once,
// all three outputs computed per block (W staged per m). Thread (tr,tc) owns
// rows tr+16*rr, cols tc*4..+3. LDS reads conflict-free; stores coalesced.
// ---------------------------------------------------------------------------
__global__ __launch_bounds__(256) void qkv_kernel(
    const float* __restrict__ x,
    const float* __restrict__ Wq, const float* __restrict__ bq,
    const float* __restrict__ Wk, const float* __restrict__ bk,
    const float* __restrict__ Wv, const float* __restrict__ bv,
    float* __restrict__ xq, float* __restrict__ xk, float* __restrict__ xv)
{
    __shared__ __align__(16) float xsh[64][68];
    __shared__ __align__(16) float wsh[64][64];
    const int tid = threadIdx.x;
    const int r0 = blockIdx.x * 64;

    // stage x tile (64 rows x 64 cols), float4 coalesced
    {
        const int row = tid >> 4, c4 = tid & 15;
        #pragma unroll
        for (int rr = 0; rr < 4; ++rr) {
            const int r = row + rr*16;
            const int gr = r0 + r;
            float4 v = (gr < NPTS) ? *(const float4*)&x[(size_t)gr*64 + c4*4]
                                   : make_float4(0.f, 0.f, 0.f, 0.f);
            *(float4*)&xsh[r][c4*4] = v;
        }
    }

    const int tr = tid >> 4, tc = tid & 15;

    for (int m = 0; m < 3; ++m) {
        const float* __restrict__ W  = (m == 0) ? Wq : (m == 1) ? Wk : Wv;
        const float* __restrict__ bs = (m == 0) ? bq : (m == 1) ? bk : bv;
        float* __restrict__ om       = (m == 0) ? xq : (m == 1) ? xk : xv;

        __syncthreads();   // previous m's readers done (also covers xsh stage)
        for (int l = tid; l < 1024; l += 256)
            *(float4*)&wsh[l >> 4][(l & 15)*4] = *(const float4*)&W[l*4];
        __syncthreads();

        float acc[4][4];
        {
            const float4 b4 = *(const float4*)&bs[tc*4];
            #pragma unroll
            for (int rr = 0; rr < 4; ++rr) {
                acc[rr][0] = b4.x; acc[rr][1] = b4.y;
                acc[rr][2] = b4.z; acc[rr][3] = b4.w;
            }
        }

        #pragma unroll 4
        for (int k4 = 0; k4 < 16; ++k4) {
            float4 xr[4];
            #pragma unroll
            for (int rr = 0; rr < 4; ++rr)
                xr[rr] = *(const float4*)&xsh[tr + 16*rr][k4*4];
            float4 wr[4];
            #pragma unroll
            for (int kk = 0; kk < 4; ++kk)
                wr[kk] = *(const float4*)&wsh[k4*4 + kk][tc*4];
            #pragma unroll
            for (int rr = 0; rr < 4; ++rr) {
                acc[rr][0] += xr[rr].x*wr[0].x + xr[rr].y*wr[1].x + xr[rr].z*wr[2].x + xr[rr].w*wr[3].x;
                acc[rr][1] += xr[rr].x*wr[0].y + xr[rr].y*wr[1].y + xr[rr].z*wr[2].y + xr[rr].w*wr[3].y;
                acc[rr][2] += xr[rr].x*wr[0].z + xr[rr].y*wr[1].z + xr[rr].z*wr[2].z + xr[rr].w*wr[3].z;
                acc[rr][3] += xr[rr].x*wr[0].w + xr[rr].y*wr[1].w + xr[rr].z*wr[2].w + xr[rr].w*wr[3].w;
            }
        }

        #pragma unroll
        for (int rr = 0; rr < 4; ++rr) {
            const int gr = r0 + tr + 16*rr;
            if (gr < NPTS) {
                float4 o;
                o.x = acc[rr][0]; o.y = acc[rr][1]; o.z = acc[rr][2]; o.w = acc[rr][3];
                *(float4*)&om[(size_t)gr*64 + tc*4] = o;
            }
        }
    }
}

// ---------------------------------------------------------------------------
// Kernel B: BN1 stats over t1 = (p[idx]-p) @ Wp1 + bp1   (3 channels)
// ---------------------------------------------------------------------------
__global__ __launch_bounds__(256) void bn1_stats_kernel(
    const float* __restrict__ p, const int* __restrict__ idx,
    const float* __restrict__ Wp1, const float* __restrict__ bp1,
    float* __restrict__ part)
{
    const int tid = threadIdx.x;
    float w9[9], bb[3];
    #pragma unroll
    for (int i = 0; i < 9; ++i) w9[i] = Wp1[i];
    #pragma unroll
    for (int i = 0; i < 3; ++i) bb[i] = bp1[i];

    float s0=0.f,s1=0.f,s2=0.f,q0=0.f,q1=0.f,q2=0.f;
    for (int row = blockIdx.x*blockDim.x + tid; row < NROWS; row += gridDim.x*blockDim.x) {
        const int n = row >> 4;
        const int j = idx[row];
        const float d0 = p[j*3+0] - p[n*3+0];
        const float d1 = p[j*3+1] - p[n*3+1];
        const float d2 = p[j*3+2] - p[n*3+2];
        const float t0 = d0*w9[0] + d1*w9[3] + d2*w9[6] + bb[0];
        const float t1 = d0*w9[1] + d1*w9[4] + d2*w9[7] + bb[1];
        const float t2 = d0*w9[2] + d1*w9[5] + d2*w9[8] + bb[2];
        s0 += t0; s1 += t1; s2 += t2;
        q0 += t0*t0; q1 += t1*t1; q2 += t2*t2;
    }
    #pragma unroll
    for (int m = 32; m >= 1; m >>= 1) {
        s0 += __shfl_xor(s0, m); s1 += __shfl_xor(s1, m); s2 += __shfl_xor(s2, m);
        q0 += __shfl_xor(q0, m); q1 += __shfl_xor(q1, m); q2 += __shfl_xor(q2, m);
    }
    __shared__ float red[4][6];
    const int lane = tid & 63, wid = tid >> 6;
    if (lane == 0) {
        red[wid][0]=s0; red[wid][1]=s1; red[wid][2]=s2;
        red[wid][3]=q0; red[wid][4]=q1; red[wid][5]=q2;
    }
    __syncthreads();
    if (tid < 6)
        part[blockIdx.x*8 + tid] = red[0][tid]+red[1][tid]+red[2][tid]+red[3][tid];
}

// ---------------------------------------------------------------------------
// BN finalize: one block per channel, 256 threads grid-stride over partials.
// ---------------------------------------------------------------------------
__global__ __launch_bounds__(256) void bn_fin_kernel(
    const float* __restrict__ part, int nblk, int stride, int nch,
    const float* __restrict__ g, const float* __restrict__ beta,
    float* __restrict__ aout, float* __restrict__ bout)
{
    const int c = blockIdx.x;
    const int tid = threadIdx.x;
    float s = 0.f, q = 0.f;
    for (int b = tid; b < nblk; b += 256) {
        s += part[(size_t)b*stride + c];
        q += part[(size_t)b*stride + nch + c];
    }
    #pragma unroll
    for (int m = 32; m >= 1; m >>= 1) { s += __shfl_xor(s, m); q += __shfl_xor(q, m); }
    __shared__ float rs[4], rq[4];
    if ((tid & 63) == 0) { rs[tid >> 6] = s; rq[tid >> 6] = q; }
    __syncthreads();
    if (tid == 0) {
        s = rs[0]+rs[1]+rs[2]+rs[3];
        q = rq[0]+rq[1]+rq[2]+rq[3];
        const float inv = 1.0f / (float)NROWS;
        const float mean = s * inv;
        const float var = fmaxf(q * inv - mean*mean, 0.f);
        const float a = g[c] * rsqrtf(var + EPS);
        aout[c] = a;
        bout[c] = beta[c] - a * mean;
    }
}

// ---------------------------------------------------------------------------
// Kernel C: BN2 stats over r_qk = xk[idx] - xq + p_r   (64 channels)
// ---------------------------------------------------------------------------
__global__ __launch_bounds__(256) void bn2_stats_kernel(
    const float* __restrict__ p, const int* __restrict__ idx,
    const float* __restrict__ xq, const float* __restrict__ xk,
    const float* __restrict__ Wp1, const float* __restrict__ bp1,
    const float* __restrict__ Wp2, const float* __restrict__ bp2,
    const float* __restrict__ st, float* __restrict__ part)
{
    const int tid = threadIdx.x, lane = tid & 63, wid = tid >> 6;
    float w9[9], bb[3], a1[3], b1[3];
    #pragma unroll
    for (int i = 0; i < 9; ++i) w9[i] = Wp1[i];
    #pragma unroll
    for (int i = 0; i < 3; ++i) { bb[i] = bp1[i]; a1[i] = st[S_BN1A+i]; b1[i] = st[S_BN1B+i]; }
    const float wc0 = Wp2[lane], wc1 = Wp2[64+lane], wc2 = Wp2[128+lane], bpc = bp2[lane];

    float s = 0.f, q = 0.f;
    const int nw = gridDim.x * 4;
    for (int pt = blockIdx.x*4 + wid; pt < NPTS; pt += nw) {
        const float xqc = xq[(size_t)pt*64 + lane];
        int jreg = 0; float h0 = 0.f, h1 = 0.f, h2 = 0.f;
        if (lane < 16) {
            jreg = idx[pt*16 + lane];
            const float pn0 = p[pt*3], pn1 = p[pt*3+1], pn2 = p[pt*3+2];
            const float d0 = p[jreg*3] - pn0, d1 = p[jreg*3+1] - pn1, d2 = p[jreg*3+2] - pn2;
            const float t0 = d0*w9[0] + d1*w9[3] + d2*w9[6] + bb[0];
            const float t1 = d0*w9[1] + d1*w9[4] + d2*w9[7] + bb[1];
            const float t2 = d0*w9[2] + d1*w9[5] + d2*w9[8] + bb[2];
            h0 = fmaxf(a1[0]*t0 + b1[0], 0.f);
            h1 = fmaxf(a1[1]*t1 + b1[1], 0.f);
            h2 = fmaxf(a1[2]*t2 + b1[2], 0.f);
        }
        #pragma unroll
        for (int t = 0; t < 16; ++t) {
            const int j = __shfl(jreg, t);
            const float g0 = __shfl(h0, t), g1 = __shfl(h1, t), g2 = __shfl(h2, t);
            const float pr = g0*wc0 + g1*wc1 + g2*wc2 + bpc;
            const float r = xk[(size_t)j*64 + lane] - xqc + pr;
            s += r; q += r*r;
        }
    }
    __shared__ float redS[4][64], redQ[4][64];
    redS[wid][lane] = s; redQ[wid][lane] = q;
    __syncthreads();
    if (tid < 64) {
        const float S = redS[0][tid]+redS[1][tid]+redS[2][tid]+redS[3][tid];
        const float Q = redQ[0][tid]+redQ[1][tid]+redQ[2][tid]+redQ[3][tid];
        part[(size_t)blockIdx.x*128 + tid] = S;
        part[(size_t)blockIdx.x*128 + 64 + tid] = Q;
    }
}

// ---------------------------------------------------------------------------
// Kernel D: w1 = relu(bn2(r_qk)) @ Ww1 + bww1  [NROWS, 8]  + BN3 stats
// wave-per-point. t-loop: lane=c computes h -> per-wave LDS slab.
// dot phase: lane=(t,j8) computes 2 outputs via float4 LDS dots.
// No block barriers in the hot loop (per-wave LDS, in-order per wave).
// ---------------------------------------------------------------------------
__global__ __launch_bounds__(256) void w1_kernel(
    const float* __restrict__ p, const int* __restrict__ idx,
    const float* __restrict__ xq, const float* __restrict__ xk,
    const float* __restrict__ Wp1, const float* __restrict__ bp1,
    const float* __restrict__ Wp2, const float* __restrict__ bp2,
    const float* __restrict__ Ww1, const float* __restrict__ bww1,
    const float* __restrict__ st, float* __restrict__ w1out, float* __restrict__ part)
{
    __shared__ __align__(16) float hl[4][16][68];   // [wave][t][c]
    __shared__ __align__(16) float wT[8][68];       // wT[j][c] = Ww1[c][j]
    const int tid = threadIdx.x, lane = tid & 63, wid = tid >> 6;

    for (int l = tid; l < 512; l += 256) wT[l & 7][l >> 3] = Ww1[l];
    __syncthreads();

    float w9[9], bb[3], a1[3], b1[3];
    #pragma unroll
    for (int i = 0; i < 9; ++i) w9[i] = Wp1[i];
    #pragma unroll
    for (int i = 0; i < 3; ++i) { bb[i] = bp1[i]; a1[i] = st[S_BN1A+i]; b1[i] = st[S_BN1B+i]; }

    const int c = lane;
    const float wc0 = Wp2[c], wc1 = Wp2[64+c], wc2 = Wp2[128+c], bpc = bp2[c];
    const float a2c = st[S_BN2A + c], b2c = st[S_BN2B + c];
    const int j8 = lane & 7, tt = lane >> 3;
    const float bw1j = bww1[j8];

    float s3 = 0.f, q3 = 0.f;
    const int nw = gridDim.x * 4;
    for (int pt = blockIdx.x*4 + wid; pt < NPTS; pt += nw) {
        const float xqc = xq[(size_t)pt*64 + lane];
        int jreg = 0; float h0 = 0.f, h1 = 0.f, h2 = 0.f;
        if (lane < 16) {
            jreg = idx[pt*16 + lane];
            const float pn0 = p[pt*3], pn1 = p[pt*3+1], pn2 = p[pt*3+2];
            const float d0 = p[jreg*3] - pn0, d1 = p[jreg*3+1] - pn1, d2 = p[jreg*3+2] - pn2;
            const float t0v = d0*w9[0] + d1*w9[3] + d2*w9[6] + bb[0];
            const float t1v = d0*w9[1] + d1*w9[4] + d2*w9[7] + bb[1];
            const float t2v = d0*w9[2] + d1*w9[5] + d2*w9[8] + bb[2];
            h0 = fmaxf(a1[0]*t0v + b1[0], 0.f);
            h1 = fmaxf(a1[1]*t1v + b1[1], 0.f);
            h2 = fmaxf(a1[2]*t2v + b1[2], 0.f);
        }
        #pragma unroll
        for (int t = 0; t < 16; ++t) {
            const int j = __shfl(jreg, t);
            const float g0 = __shfl(h0, t), g1 = __shfl(h1, t), g2 = __shfl(h2, t);
            const float pr = g0*wc0 + g1*wc1 + g2*wc2 + bpc;
            const float r = xk[(size_t)j*64 + lane] - xqc + pr;
            hl[wid][t][lane] = fmaxf(a2c*r + b2c, 0.f);
        }
        __builtin_amdgcn_sched_barrier(0);   // keep ds_writes before dot reads

        float acc0 = bw1j, acc1 = bw1j;
        const float4* h0p = (const float4*)&hl[wid][tt][0];
        const float4* h1p = (const float4*)&hl[wid][tt + 8][0];
        const float4* wp  = (const float4*)&wT[j8][0];
        #pragma unroll
        for (int k = 0; k < 16; ++k) {
            const float4 w4 = wp[k];
            const float4 a4 = h0p[k];
            const float4 b4 = h1p[k];
            acc0 += a4.x*w4.x + a4.y*w4.y + a4.z*w4.z + a4.w*w4.w;
            acc1 += b4.x*w4.x + b4.y*w4.y + b4.z*w4.z + b4.w*w4.w;
        }
        w1out[(size_t)pt*128 + lane]      = acc0;   // (pt*16+tt)*8 + j8
        w1out[(size_t)pt*128 + 64 + lane] = acc1;   // (pt*16+tt+8)*8 + j8
        s3 += acc0 + acc1;
        q3 += acc0*acc0 + acc1*acc1;
        __builtin_amdgcn_sched_barrier(0);   // keep dot reads before next writes
    }

    // stats: lane's values all belong to channel j8; fold t-groups
    s3 += __shfl_xor(s3, 8);  q3 += __shfl_xor(q3, 8);
    s3 += __shfl_xor(s3, 16); q3 += __shfl_xor(q3, 16);
    s3 += __shfl_xor(s3, 32); q3 += __shfl_xor(q3, 32);
    __shared__ float redS[4][8], redQ[4][8];
    if (lane < 8) { redS[wid][lane] = s3; redQ[wid][lane] = q3; }
    __syncthreads();
    if (tid < 8) {
        const float S = redS[0][tid]+redS[1][tid]+redS[2][tid]+redS[3][tid];
        const float Q = redQ[0][tid]+redQ[1][tid]+redQ[2][tid]+redQ[3][tid];
        part[(size_t)blockIdx.x*16 + tid]     = S;
        part[(size_t)blockIdx.x*16 + 8 + tid] = Q;
    }
}

// ---------------------------------------------------------------------------
// Kernel E: w2 = relu(bn3(w1)) @ Ww2 + bww2; softmax; weighted sum.
// ---------------------------------------------------------------------------
__global__ __launch_bounds__(256) void out_kernel(
    const float* __restrict__ p, const int* __restrict__ idx,
    const float* __restrict__ xv, const float* __restrict__ w1,
    const float* __restrict__ Wp1, const float* __restrict__ bp1,
    const float* __restrict__ Wp2, const float* __restrict__ bp2,
    const float* __restrict__ Ww2, const float* __restrict__ bww2,
    const float* __restrict__ st, float* __restrict__ out)
{
    const int tid = threadIdx.x, lane = tid & 63, wid = tid >> 6;
    const int j8 = lane & 7, t0 = lane >> 3;

    float w9[9], bb[3], a1[3], b1[3];
    #pragma unroll
    for (int i = 0; i < 9; ++i) w9[i] = Wp1[i];
    #pragma unroll
    for (int i = 0; i < 3; ++i) { bb[i] = bp1[i]; a1[i] = st[S_BN1A+i]; b1[i] = st[S_BN1B+i]; }
    float a3[8], b3[8], ww2c[8];
    #pragma unroll
    for (int i = 0; i < 8; ++i) {
        a3[i] = st[S_BN3A+i]; b3[i] = st[S_BN3B+i];
        ww2c[i] = Ww2[i*8 + j8];
    }
    const float bw2j = bww2[j8];
    const int c = lane;
    const float wc0 = Wp2[c], wc1 = Wp2[64+c], wc2 = Wp2[128+c], bpc = bp2[c];

    const int nw = gridDim.x * 4;
    for (int pt = blockIdx.x*4 + wid; pt < NPTS; pt += nw) {
        int jreg = 0; float h0 = 0.f, h1 = 0.f, h2 = 0.f;
        if (lane < 16) {
            jreg = idx[pt*16 + lane];
            const float pn0 = p[pt*3], pn1 = p[pt*3+1], pn2 = p[pt*3+2];
            const float d0 = p[jreg*3] - pn0, d1 = p[jreg*3+1] - pn1, d2 = p[jreg*3+2] - pn2;
            const float t1v = d0*w9[0] + d1*w9[3] + d2*w9[6] + bb[0];
            const float t2v = d0*w9[1] + d1*w9[4] + d2*w9[7] + bb[1];
            const float t3v = d0*w9[2] + d1*w9[5] + d2*w9[8] + bb[2];
            h0 = fmaxf(a1[0]*t1v + b1[0], 0.f);
            h1 = fmaxf(a1[1]*t2v + b1[1], 0.f);
            h2 = fmaxf(a1[2]*t3v + b1[2], 0.f);
        }

        const float* w1r0 = &w1[(size_t)(pt*16 + t0)*8];
        float v0 = bw2j, v1 = bw2j;
        #pragma unroll
        for (int jj = 0; jj < 8; ++jj) {
            v0 += fmaxf(a3[jj]*w1r0[jj]      + b3[jj], 0.f) * ww2c[jj];
            v1 += fmaxf(a3[jj]*w1r0[64 + jj] + b3[jj], 0.f) * ww2c[jj];
        }
        float m = fmaxf(v0, v1);
        m = fmaxf(m, __shfl_xor(m, 8));
        m = fmaxf(m, __shfl_xor(m, 16));
        m = fmaxf(m, __shfl_xor(m, 32));
        float e0 = __expf(v0 - m), e1 = __expf(v1 - m);
        float ssum = e0 + e1;
        ssum += __shfl_xor(ssum, 8);
        ssum += __shfl_xor(ssum, 16);
        ssum += __shfl_xor(ssum, 32);
        const float inv = 1.0f / ssum;
        e0 *= inv; e1 *= inv;

        float acc = 0.f;
        #pragma unroll
        for (int t = 0; t < 16; ++t) {
            const int j = __shfl(jreg, t);
            const float g0 = __shfl(h0, t), g1 = __shfl(h1, t), g2 = __shfl(h2, t);
            const float pr = g0*wc0 + g1*wc1 + g2*wc2 + bpc;
            const float wt = __shfl((t < 8) ? e0 : e1, ((t & 7) << 3) + j8);
            acc += (xv[(size_t)j*64 + c] + pr) * wt;
        }
        out[(size_t)pt*64 + c] = acc;
    }
}

// ---------------------------------------------------------------------------
extern "C" void kernel_launch(void* const* d_in, const int* in_sizes, int n_in,
                              void* d_out, int out_size, void* d_ws, size_t ws_size,
                              hipStream_t stream)
{
    const float* p    = (const float*)d_in[0];
    const float* x    = (const float*)d_in[1];
    const int*   idx  = (const int*)d_in[3];
    const float* Wq   = (const float*)d_in[4];
    const float* bq   = (const float*)d_in[5];
    const float* Wk   = (const float*)d_in[6];
    const float* bk   = (const float*)d_in[7];
    const float* Wv   = (const float*)d_in[8];
    const float* bv   = (const float*)d_in[9];
    const float* Wp1  = (const float*)d_in[10];
    const float* bp1  = (const float*)d_in[11];
    const float* gp   = (const float*)d_in[12];
    const float* betap= (const float*)d_in[13];
    const float* Wp2  = (const float*)d_in[14];
    const float* bp2  = (const float*)d_in[15];
    const float* gw1  = (const float*)d_in[16];
    const float* bw1  = (const float*)d_in[17];
    const float* Ww1  = (const float*)d_in[18];
    const float* bww1 = (const float*)d_in[19];
    const float* gw2  = (const float*)d_in[20];
    const float* bw2  = (const float*)d_in[21];
    const float* Ww2  = (const float*)d_in[22];
    const float* bww2 = (const float*)d_in[23];

    float* out = (float*)d_out;
    float* ws  = (float*)d_ws;

    float* xq = ws;
    float* xk = ws + (size_t)NPTS*64;
    float* xv = ws + (size_t)2*NPTS*64;
    float* w1 = ws + (size_t)3*NPTS*64;
    float* st = ws + (size_t)3*NPTS*64 + (size_t)NROWS*8;

    qkv_kernel<<<(NPTS + 63)/64, 256, 0, stream>>>(x, Wq, bq, Wk, bk, Wv, bv, xq, xk, xv);

    bn1_stats_kernel<<<GRID_B, 256, 0, stream>>>(p, idx, Wp1, bp1, st + S_PARTB);
    bn_fin_kernel<<<3, 256, 0, stream>>>(st + S_PARTB, GRID_B, 8, 3, gp, betap,
                                         st + S_BN1A, st + S_BN1B);

    bn2_stats_kernel<<<GRID_C, 256, 0, stream>>>(p, idx, xq, xk, Wp1, bp1, Wp2, bp2,
                                                 st, st + S_PARTC);
    bn_fin_kernel<<<64, 256, 0, stream>>>(st + S_PARTC, GRID_C, 128, 64, gw1, bw1,
                                          st + S_BN2A, st + S_BN2B);

    w1_kernel<<<GRID_D, 256, 0, stream>>>(p, idx, xq, xk, Wp1, bp1, Wp2, bp2,
                                          Ww1, bww1, st, w1, st + S_PARTD);
    bn_fin_kernel<<<8, 256, 0, stream>>>(st + S_PARTD, GRID_D, 16, 8, gw2, bw2,
                                         st + S_BN3A, st + S_BN3B);

    out_kernel<<<GRID_E, 256, 0, stream>>>(p, idx, xv, w1, Wp1, bp1, Wp2, bp2,
                                           Ww2, bww2, st, out);
}